// Round 3
// baseline (563.581 us; speedup 1.0000x reference)
//
#include <hip/hip_runtime.h>
#include <hip/hip_bf16.h>
#include <math.h>

// ---------------------------------------------------------------------------
// Round 12. R11 measured 525.4us (attn 106.9, MfmaUtil 27.4/VALU 43).
// GEMM side only gained ~10us from gload_lds: short-K (K=1024, 32 iters)
// amortizes per-block overhead poorly. Dominant remaining waste: steps 4+5
// read the same A (out1b) twice and roundtrip 128MB of fp32 x2 via HBM.
// Change: fused mgemm_glu (w1+w2 in one kernel):
//   - stages A + B1 + B2 per K-step (LDS 24KB), A-frags reused for two
//     acc sets (32 MFMA/wave/K-step), silu(x1)*x2 in registers.
//   - eliminates x2 entirely (64MB write + 64MB read + extra A pass).
// attn / mgemm / mgemm_qkv unchanged (proven R11).
// ---------------------------------------------------------------------------

#define SEQ     2048
#define BATCH   4
#define NH      16
#define CDIM    1024
#define MROWS   8192

typedef __bf16 bf16x8 __attribute__((ext_vector_type(8)));
typedef float  floatx4 __attribute__((ext_vector_type(4)));
typedef float  floatx16 __attribute__((ext_vector_type(16)));
typedef unsigned int u32;

__device__ __forceinline__ unsigned short f2bf(float f) {
    __bf16 h = (__bf16)f;                      // RNE, HW cvt on gfx950
    return __builtin_bit_cast(unsigned short, h);
}
__device__ __forceinline__ float fexp2(float x) {   // 2^x
    float r; asm("v_exp_f32 %0, %1" : "=v"(r) : "v"(x)); return r;
}
__device__ __forceinline__ floatx4 mfma16(bf16x8 a, bf16x8 b, floatx4 c) {
    return __builtin_amdgcn_mfma_f32_16x16x32_bf16(a, b, c, 0, 0, 0);
}
__device__ __forceinline__ floatx16 mfma32(bf16x8 a, bf16x8 b, floatx16 c) {
    return __builtin_amdgcn_mfma_f32_32x32x16_bf16(a, b, c, 0, 0, 0);
}
// async global->LDS, 16B/lane; LDS dest wave-uniform base + lane*16
__device__ __forceinline__ void gld16(void* lds, const void* g) {
    __builtin_amdgcn_global_load_lds(
        (const __attribute__((address_space(1))) u32*)g,
        (__attribute__((address_space(3))) u32*)lds, 16, 0, 0);
}

// ============================================================
// bf16 MFMA GEMM NT, m97-style gload_lds staging:
// C[m,n] = sum_k A[m,k]*B[n,k] (+bias) (+GLU with fp32 x2)
// ============================================================
template <int OUTMODE, bool BIAS, bool GLU>
__global__ __launch_bounds__(256) void mgemm(
    const unsigned short* __restrict__ A,
    const unsigned short* __restrict__ B,
    const float* __restrict__ bias,
    void* __restrict__ C, int ldc,
    const float* __restrict__ x2, int ldx,
    int K)
{
    __shared__ __align__(16) unsigned short As[128 * 32];
    __shared__ __align__(16) unsigned short Bs[128 * 32];

    const int tid  = threadIdx.x;
    const int lane = tid & 63;
    const int wave = tid >> 6;
    const int l16  = lane & 15;
    const int quad = lane >> 4;
    const int wm = (wave >> 1) * 64, wn = (wave & 1) * 64;
    const int bm = blockIdx.y, bn = blockIdx.x;

    const unsigned short* Ag = A + (size_t)(bm * 128) * K;
    const unsigned short* Bg = B + (size_t)(bn * 128) * K;

    // gload geometry: wave w call j -> LDS rows (w*2+j)*16..+15 (1KB/call)
    const int srow0 = wave * 32 + (lane >> 2);
    const int scol  = (lane & 3) * 8;
    unsigned short* lA0 = As + (wave * 2 + 0) * 512;
    unsigned short* lA1 = As + (wave * 2 + 1) * 512;
    unsigned short* lB0 = Bs + (wave * 2 + 0) * 512;
    unsigned short* lB1 = Bs + (wave * 2 + 1) * 512;
    const unsigned short* gA0 = Ag + (size_t)srow0 * K + scol;
    const unsigned short* gA1 = Ag + (size_t)(srow0 + 16) * K + scol;
    const unsigned short* gB0 = Bg + (size_t)srow0 * K + scol;
    const unsigned short* gB1 = Bg + (size_t)(srow0 + 16) * K + scol;

    floatx4 acc[4][4] = {};

    for (int kt = 0; kt < K; kt += 32) {
        __syncthreads();                 // prev tile's frag reads complete
        gld16(lA0, gA0 + kt);
        gld16(lA1, gA1 + kt);
        gld16(lB0, gB0 + kt);
        gld16(lB1, gB1 + kt);
        __syncthreads();                 // vmcnt drained -> tile ready

        bf16x8 af[4], bfr[4];
        #pragma unroll
        for (int mt = 0; mt < 4; ++mt)
            af[mt] = *(const bf16x8*)&As[(wm + mt * 16 + l16) * 32 + quad * 8];
        #pragma unroll
        for (int nt = 0; nt < 4; ++nt)
            bfr[nt] = *(const bf16x8*)&Bs[(wn + nt * 16 + l16) * 32 + quad * 8];
        #pragma unroll
        for (int mt = 0; mt < 4; ++mt)
            #pragma unroll
            for (int nt = 0; nt < 4; ++nt)
                acc[mt][nt] = mfma16(af[mt], bfr[nt], acc[mt][nt]);
    }

    #pragma unroll
    for (int nt = 0; nt < 4; ++nt) {
        const int gcol = bn * 128 + wn + nt * 16 + l16;
        const float bv = BIAS ? bias[gcol] : 0.0f;
        #pragma unroll
        for (int mt = 0; mt < 4; ++mt) {
            #pragma unroll
            for (int r = 0; r < 4; ++r) {
                const int grow = bm * 128 + wm + mt * 16 + quad * 4 + r;
                float v = acc[mt][nt][r] + bv;
                if (GLU)
                    v = (v / (1.0f + expf(-v))) * x2[(size_t)grow * ldx + gcol];
                if (OUTMODE == 0)
                    ((float*)C)[(size_t)grow * ldc + gcol] = v;
                else
                    ((unsigned short*)C)[(size_t)grow * ldc + gcol] = f2bf(v);
            }
        }
    }
}

// ============================================================
// Fused SwiGLU GEMM: hid[m,n] = silu(A@W1^T + b1) * (A@W2^T + b2)
// Stages A once per K-step; A-frags feed two accumulator sets.
// LDS 24KB; 32 MFMA/wave/K-step.
// ============================================================
__global__ __launch_bounds__(256) void mgemm_glu(
    const unsigned short* __restrict__ A,
    const unsigned short* __restrict__ B1,
    const unsigned short* __restrict__ B2,
    const float* __restrict__ bias1,
    const float* __restrict__ bias2,
    unsigned short* __restrict__ C, int ldc,
    int K)
{
    __shared__ __align__(16) unsigned short As[128 * 32];
    __shared__ __align__(16) unsigned short B1s[128 * 32];
    __shared__ __align__(16) unsigned short B2s[128 * 32];

    const int tid  = threadIdx.x;
    const int lane = tid & 63;
    const int wave = tid >> 6;
    const int l16  = lane & 15;
    const int quad = lane >> 4;
    const int wm = (wave >> 1) * 64, wn = (wave & 1) * 64;
    const int bm = blockIdx.y, bn = blockIdx.x;

    const unsigned short* Ag  = A  + (size_t)(bm * 128) * K;
    const unsigned short* B1g = B1 + (size_t)(bn * 128) * K;
    const unsigned short* B2g = B2 + (size_t)(bn * 128) * K;

    const int srow0 = wave * 32 + (lane >> 2);
    const int scol  = (lane & 3) * 8;
    unsigned short* lA0  = As  + (wave * 2 + 0) * 512;
    unsigned short* lA1  = As  + (wave * 2 + 1) * 512;
    unsigned short* lB10 = B1s + (wave * 2 + 0) * 512;
    unsigned short* lB11 = B1s + (wave * 2 + 1) * 512;
    unsigned short* lB20 = B2s + (wave * 2 + 0) * 512;
    unsigned short* lB21 = B2s + (wave * 2 + 1) * 512;
    const unsigned short* gA0  = Ag  + (size_t)srow0 * K + scol;
    const unsigned short* gA1  = Ag  + (size_t)(srow0 + 16) * K + scol;
    const unsigned short* gB10 = B1g + (size_t)srow0 * K + scol;
    const unsigned short* gB11 = B1g + (size_t)(srow0 + 16) * K + scol;
    const unsigned short* gB20 = B2g + (size_t)srow0 * K + scol;
    const unsigned short* gB21 = B2g + (size_t)(srow0 + 16) * K + scol;

    floatx4 acc1[4][4] = {};
    floatx4 acc2[4][4] = {};

    for (int kt = 0; kt < K; kt += 32) {
        __syncthreads();
        gld16(lA0,  gA0  + kt);
        gld16(lA1,  gA1  + kt);
        gld16(lB10, gB10 + kt);
        gld16(lB11, gB11 + kt);
        gld16(lB20, gB20 + kt);
        gld16(lB21, gB21 + kt);
        __syncthreads();

        bf16x8 af[4], bf1[4], bf2[4];
        #pragma unroll
        for (int mt = 0; mt < 4; ++mt)
            af[mt] = *(const bf16x8*)&As[(wm + mt * 16 + l16) * 32 + quad * 8];
        #pragma unroll
        for (int nt = 0; nt < 4; ++nt) {
            bf1[nt] = *(const bf16x8*)&B1s[(wn + nt * 16 + l16) * 32 + quad * 8];
            bf2[nt] = *(const bf16x8*)&B2s[(wn + nt * 16 + l16) * 32 + quad * 8];
        }
        #pragma unroll
        for (int mt = 0; mt < 4; ++mt)
            #pragma unroll
            for (int nt = 0; nt < 4; ++nt) {
                acc1[mt][nt] = mfma16(af[mt], bf1[nt], acc1[mt][nt]);
                acc2[mt][nt] = mfma16(af[mt], bf2[nt], acc2[mt][nt]);
            }
    }

    #pragma unroll
    for (int nt = 0; nt < 4; ++nt) {
        const int gcol = bn * 128 + wn + nt * 16 + l16;
        const float b1 = bias1[gcol];
        const float b2 = bias2[gcol];
        #pragma unroll
        for (int mt = 0; mt < 4; ++mt) {
            #pragma unroll
            for (int r = 0; r < 4; ++r) {
                const int grow = bm * 128 + wm + mt * 16 + quad * 4 + r;
                const float x1 = acc1[mt][nt][r] + b1;
                const float x2 = acc2[mt][nt][r] + b2;
                const float v = (x1 / (1.0f + expf(-x1))) * x2;
                C[(size_t)grow * ldc + gcol] = f2bf(v);
            }
        }
    }
}

// ============================================================
// QKV GEMM (gload_lds staging), fused epilogues:
//  q/k: fp32 RoPE (table), q pre-scaled by 0.125*log2e, -> Qb/Kb [bh][n][64]
//  v:   LDS-transposed (reuses dead As) -> Vtb [bh][d][n], 16B stores
// ============================================================
__global__ __launch_bounds__(256) void mgemm_qkv(
    const unsigned short* __restrict__ A,
    const unsigned short* __restrict__ B,
    const float* __restrict__ tab,
    unsigned short* __restrict__ Qb,
    unsigned short* __restrict__ Kb,
    unsigned short* __restrict__ Vtb)
{
    __shared__ __align__(16) unsigned short As[128 * 32];
    __shared__ __align__(16) unsigned short Bs[128 * 32];

    const int tid  = threadIdx.x;
    const int lane = tid & 63;
    const int wave = tid >> 6;
    const int l16  = lane & 15;
    const int quad = lane >> 4;
    const int wm = (wave >> 1) * 64, wn = (wave & 1) * 64;
    const int bm = blockIdx.y, bn = blockIdx.x;
    const int K = CDIM;

    const unsigned short* Ag = A + (size_t)(bm * 128) * K;
    const unsigned short* Bg = B + (size_t)(bn * 128) * K;

    const int srow0 = wave * 32 + (lane >> 2);
    const int scol  = (lane & 3) * 8;
    unsigned short* lA0 = As + (wave * 2 + 0) * 512;
    unsigned short* lA1 = As + (wave * 2 + 1) * 512;
    unsigned short* lB0 = Bs + (wave * 2 + 0) * 512;
    unsigned short* lB1 = Bs + (wave * 2 + 1) * 512;
    const unsigned short* gA0 = Ag + (size_t)srow0 * K + scol;
    const unsigned short* gA1 = Ag + (size_t)(srow0 + 16) * K + scol;
    const unsigned short* gB0 = Bg + (size_t)srow0 * K + scol;
    const unsigned short* gB1 = Bg + (size_t)(srow0 + 16) * K + scol;

    floatx4 acc[4][4] = {};

    for (int kt = 0; kt < K; kt += 32) {
        __syncthreads();
        gld16(lA0, gA0 + kt);
        gld16(lA1, gA1 + kt);
        gld16(lB0, gB0 + kt);
        gld16(lB1, gB1 + kt);
        __syncthreads();

        bf16x8 af[4], bfr[4];
        #pragma unroll
        for (int mt = 0; mt < 4; ++mt)
            af[mt] = *(const bf16x8*)&As[(wm + mt * 16 + l16) * 32 + quad * 8];
        #pragma unroll
        for (int nt = 0; nt < 4; ++nt)
            bfr[nt] = *(const bf16x8*)&Bs[(wn + nt * 16 + l16) * 32 + quad * 8];
        #pragma unroll
        for (int mt = 0; mt < 4; ++mt)
            #pragma unroll
            for (int nt = 0; nt < 4; ++nt)
                acc[mt][nt] = mfma16(af[mt], bfr[nt], acc[mt][nt]);
    }

    // part is BLOCK-uniform: 128-col blocks never straddle a 1024 boundary.
    const int colbase0 = bn * 128;
    const int part = colbase0 >> 10;            // 0=q 1=k 2=v

    if (part == 2) {
        // ---- V: transpose via LDS (As dead), write Vtb [bh][d][n] ----
        unsigned short* T = As;                 // 4 waves x 64d x 16n ushorts
        #pragma unroll
        for (int mt = 0; mt < 4; ++mt) {
            __syncthreads();
            #pragma unroll
            for (int nt = 0; nt < 4; ++nt) {
                ushort4 pk;
                pk.x = f2bf(acc[mt][nt][0]); pk.y = f2bf(acc[mt][nt][1]);
                pk.z = f2bf(acc[mt][nt][2]); pk.w = f2bf(acc[mt][nt][3]);
                *(ushort4*)&T[((wave * 64 + nt * 16 + l16) * 16) + quad * 4] = pk;
            }
            __syncthreads();
            // 256 threads: w2 = tid>>6 (wave-tile), d = tid&63; 32B per thread
            const int w2 = tid >> 6, d = tid & 63;
            const int nrow0 = bm * 128 + (w2 >> 1) * 64 + mt * 16;
            const int b = nrow0 >> 11, n0 = nrow0 & 2047;
            const int h2 = ((bn * 128 + (w2 & 1) * 64) & 1023) >> 6;
            unsigned short* dst = Vtb +
                ((size_t)(b * NH + h2) * 64 + d) * 2048 + n0;
            const int tb = (w2 * 64 + d) * 16;
            *(uint4*)dst       = *(const uint4*)&T[tb];
            *(uint4*)(dst + 8) = *(const uint4*)&T[tb + 8];
        }
    } else {
        // ---- q/k: fp32 RoPE; q scaled by 0.125*log2e (exp2 softmax) ----
        const float qscale = (part == 0) ? 0.125f * 1.44269504088896f : 1.0f;
        const int h = ((colbase0 + wn) & 1023) >> 6;
        #pragma unroll
        for (int mt = 0; mt < 4; ++mt) {
            #pragma unroll
            for (int r = 0; r < 4; ++r) {
                const int grow = bm * 128 + wm + mt * 16 + quad * 4 + r;
                const int b = grow >> 11, n = grow & 2047;
                unsigned short* dst =
                    (part == 0 ? Qb : Kb) + ((size_t)(b * NH + h) * 2048 + n) * 64;
                #pragma unroll
                for (int nt = 0; nt < 2; ++nt) {
                    const int i = nt * 16 + l16;          // 0..31
                    const float c  = tab[(n * 32 + i) * 2];
                    const float sn = tab[(n * 32 + i) * 2 + 1];
                    const float x1 = acc[mt][nt][r];
                    const float x2v = acc[mt][nt + 2][r];
                    dst[i]      = f2bf((x1 * c - x2v * sn) * qscale);
                    dst[i + 32] = f2bf((x2v * c + x1 * sn) * qscale);
                }
            }
        }
    }
}

// ============================================================
// MFMA flash attention v3.1 (unchanged from R11): 128-query blocks,
// 32x32x16 MFMA, P = exp2(S) with log2e folded into Q, T14 prefetch.
// ============================================================
__global__ __launch_bounds__(256) void attn_mfma(
    const unsigned short* __restrict__ Qb,
    const unsigned short* __restrict__ Kb,
    const unsigned short* __restrict__ Vtb,
    unsigned short* __restrict__ Ob)
{
    const int qt = blockIdx.x;        // 0..15
    const int bh = blockIdx.y;        // 0..63
    const int tid = threadIdx.x;
    const int lane = tid & 63, wave = tid >> 6;
    const int r32 = lane & 31, hi = lane >> 5;
    const int q0 = wave * 32;
    const int qrow = q0 + r32;        // this lane's query row in LDS

    __shared__ unsigned short QP[128][72];  // Q staging, then P [q][key]
    __shared__ unsigned short Ks[64][72];   // K tile [key][dim]
    __shared__ unsigned short Vs[64][72];   // V^T tile [dim][key]

    const unsigned short* Qg = Qb + ((size_t)bh * 2048 + qt * 128) * 64;
    const unsigned short* Kg = Kb + (size_t)bh * 2048 * 64;
    const unsigned short* Vg = Vtb + (size_t)bh * 64 * 2048;

    // stage Q tile 128x64
    #pragma unroll
    for (int rep = 0; rep < 4; ++rep) {
        const int c = tid + rep * 256;
        const int r = c >> 3, d0 = (c & 7) * 8;
        *(uint4*)&QP[r][d0] = *(const uint4*)(Qg + (size_t)r * 64 + d0);
    }

    // K/V staging slots for this thread (2 b128 each per tile)
    const int c0 = tid, c1 = tid + 256;
    const int kr0 = c0 >> 3, kd0 = (c0 & 7) * 8;
    const int kr1 = c1 >> 3, kd1 = (c1 & 7) * 8;

    // T14 prefetch tile 0 into regs
    uint4 ka0 = *(const uint4*)(Kg + (size_t)kr0 * 64 + kd0);
    uint4 ka1 = *(const uint4*)(Kg + (size_t)kr1 * 64 + kd1);
    uint4 va0 = *(const uint4*)(Vg + (size_t)kr0 * 2048 + kd0);
    uint4 va1 = *(const uint4*)(Vg + (size_t)kr1 * 2048 + kd1);

    __syncthreads();   // Q tile ready

    // Q B-frags (rows = wave's 32 queries), held for all iterations
    bf16x8 bq[4];
    #pragma unroll
    for (int f = 0; f < 4; ++f)
        bq[f] = *(const bf16x8*)&QP[qrow][f * 16 + hi * 8];

    floatx16 o0 = {}, o1 = {};      // O^T[d][q]: d-tiles 0..31 / 32..63
    float l_acc = 0.0f;

    for (int kt = 0; kt < 32; ++kt) {
        __syncthreads();   // prev tile's Ks/Vs frag reads complete
        *(uint4*)&Ks[kr0][kd0] = ka0;
        *(uint4*)&Ks[kr1][kd1] = ka1;
        *(uint4*)&Vs[kr0][kd0] = va0;
        *(uint4*)&Vs[kr1][kd1] = va1;
        if (kt + 1 < 32) {           // T14: issue next-tile loads now,
            const size_t nb = (size_t)(kt + 1) * 64;     // land during compute
            ka0 = *(const uint4*)(Kg + (nb + kr0) * 64 + kd0);
            ka1 = *(const uint4*)(Kg + (nb + kr1) * 64 + kd1);
            va0 = *(const uint4*)(Vg + (size_t)kr0 * 2048 + nb + kd0);
            va1 = *(const uint4*)(Vg + (size_t)kr1 * 2048 + nb + kd1);
        }
        __syncthreads();   // tile ready

        // ---- S^T (2 key subtiles of 32) + exp2 + P write + rowsum ----
        #pragma unroll
        for (int t = 0; t < 2; ++t) {
            floatx16 s = {};
            #pragma unroll
            for (int f = 0; f < 4; ++f) {
                const bf16x8 ak = *(const bf16x8*)&Ks[t * 32 + r32][f * 16 + hi * 8];
                s = mfma32(ak, bq[f], s);
            }
            float rs = 0.0f;
            #pragma unroll
            for (int g = 0; g < 4; ++g) {
                const float p0 = fexp2(s[4 * g + 0]);
                const float p1 = fexp2(s[4 * g + 1]);
                const float p2 = fexp2(s[4 * g + 2]);
                const float p3 = fexp2(s[4 * g + 3]);
                rs += (p0 + p1) + (p2 + p3);
                ushort4 pk;
                pk.x = f2bf(p0); pk.y = f2bf(p1); pk.z = f2bf(p2); pk.w = f2bf(p3);
                // key = t*32 + 8g + 4*hi + (0..3)
                *(ushort4*)&QP[qrow][t * 32 + 8 * g + 4 * hi] = pk;
            }
            l_acc += rs;
        }

        // ---- O^T += V^T P^T (same-wave LDS RAW: in-order DS pipe) ----
        bf16x8 bp[4];
        #pragma unroll
        for (int f = 0; f < 4; ++f)
            bp[f] = *(const bf16x8*)&QP[qrow][f * 16 + hi * 8];
        #pragma unroll
        for (int f = 0; f < 4; ++f) {
            const bf16x8 av0 = *(const bf16x8*)&Vs[r32][f * 16 + hi * 8];
            o0 = mfma32(av0, bp[f], o0);
            const bf16x8 av1 = *(const bf16x8*)&Vs[32 + r32][f * 16 + hi * 8];
            o1 = mfma32(av1, bp[f], o1);
        }
    }

    // epilogue: lane's query = q0 + r32; lanes l/l+32 hold disjoint key
    // halves of the same query -> one shfl to complete l.
    const float l_tot = l_acc + __shfl_xor(l_acc, 32);
    const float inv = 1.0f / l_tot;
    const int b = bh >> 4, h = bh & 15;
    unsigned short* orow = Ob +
        (size_t)(b * SEQ + qt * 128 + qrow) * CDIM + h * 64;
    #pragma unroll
    for (int u = 0; u < 2; ++u) {
        const floatx16 ov = u ? o1 : o0;
        #pragma unroll
        for (int g = 0; g < 4; ++g) {
            ushort4 pk;
            pk.x = f2bf(ov[4 * g + 0] * inv); pk.y = f2bf(ov[4 * g + 1] * inv);
            pk.z = f2bf(ov[4 * g + 2] * inv); pk.w = f2bf(ov[4 * g + 3] * inv);
            // d = u*32 + 8g + 4*hi + (0..3)
            *(ushort4*)(orow + u * 32 + 8 * g + 4 * hi) = pk;
        }
    }
}

// ============================================================
// fp32 -> bf16 converter; RoPE table (fp64 angles)
// ============================================================
__global__ __launch_bounds__(256) void cvt_bf16(
    const float* __restrict__ src, unsigned short* __restrict__ dst)
{
    const size_t i = ((size_t)blockIdx.x * 256 + threadIdx.x) * 4;
    const float4 f = *(const float4*)(src + i);
    ushort4 o; o.x = f2bf(f.x); o.y = f2bf(f.y); o.z = f2bf(f.z); o.w = f2bf(f.w);
    *(ushort4*)(dst + i) = o;
}

__global__ __launch_bounds__(256) void rope_table(float* __restrict__ tab)
{
    const int idx = blockIdx.x * 256 + threadIdx.x;   // < 65536
    const int i = idx & 31, n = idx >> 5;
    const double f = (double)n * pow(10000.0, -(double)(2 * i) / 64.0);
    tab[idx * 2]     = (float)cos(f);
    tab[idx * 2 + 1] = (float)sin(f);
}

// ============================================================
// kernel_launch
// ============================================================
extern "C" void kernel_launch(void* const* d_in, const int* in_sizes, int n_in,
                              void* d_out, int out_size, void* d_ws, size_t ws_size,
                              hipStream_t stream)
{
    const float* x      = (const float*)d_in[0];
    const float* qkv_w  = (const float*)d_in[1];
    const float* proj_w = (const float*)d_in[2];
    const float* proj_b = (const float*)d_in[3];
    const float* w1_w   = (const float*)d_in[4];
    const float* w1_b   = (const float*)d_in[5];
    const float* w2_w   = (const float*)d_in[6];
    const float* w2_b   = (const float*)d_in[7];
    const float* w3_w   = (const float*)d_in[8];
    const float* w3_b   = (const float*)d_in[9];
    float* out = (float*)d_out;

    char* ws = (char*)d_ws;
    unsigned short* Qb    = (unsigned short*)(ws);              // [0,16M)
    unsigned short* Kb    = (unsigned short*)(ws + 16777216);   // [16,32M)
    unsigned short* Vtb   = (unsigned short*)(ws + 33554432);   // [32,48M)
    unsigned short* Ob    = (unsigned short*)(ws + 50331648);   // [48,64M)
    unsigned short* out1b = (unsigned short*)(ws + 67108864);   // [64,80M)
    unsigned short* w1b   = (unsigned short*)(ws + 83886080);   // [80,84M)
    unsigned short* w2b   = (unsigned short*)(ws + 88080384);   // [84,88M)
    unsigned short* w3b   = (unsigned short*)(ws + 92274688);   // [88,92M)
    unsigned short* projb = (unsigned short*)(ws + 96468992);   // [92,94M)
    unsigned short* xb    = (unsigned short*)(ws + 98566144);   // [94,110M)
    unsigned short* wqkvb = (unsigned short*)(ws + 115343360);  // [110,116M)
    float*          tab   = (float*)(ws + 121634816);           // [116,116.5M)
    unsigned short* hid   = (unsigned short*)(ws);              // [0,32M) (x2 gone)

    const dim3 blk(256);

    cvt_bf16<<<dim3(8192), blk, 0, stream>>>(x, xb);
    cvt_bf16<<<dim3(3072), blk, 0, stream>>>(qkv_w, wqkvb);
    cvt_bf16<<<dim3(1024), blk, 0, stream>>>(proj_w, projb);
    cvt_bf16<<<dim3(2048), blk, 0, stream>>>(w1_w, w1b);
    cvt_bf16<<<dim3(2048), blk, 0, stream>>>(w2_w, w2b);
    cvt_bf16<<<dim3(2048), blk, 0, stream>>>(w3_w, w3b);
    rope_table<<<dim3(256), blk, 0, stream>>>(tab);

    // 1) QKV GEMM + fused rope/scale + coalesced transpose scatter
    mgemm_qkv<<<dim3(24, 64), blk, 0, stream>>>(xb, wqkvb, tab, Qb, Kb, Vtb);
    // 2) MFMA flash attention (128-query blocks) -> Ob bf16 [8192,1024]
    attn_mfma<<<dim3(SEQ / 128, BATCH * NH), blk, 0, stream>>>(Qb, Kb, Vtb, Ob);
    // 3) out1b = Ob @ projb^T + proj_b (bf16)
    mgemm<1, true, false><<<dim3(8, 64), blk, 0, stream>>>(
        Ob, projb, proj_b, out1b, CDIM, nullptr, 0, CDIM);
    // 4) hid = silu(out1b@w1^T + b1) * (out1b@w2^T + b2)  [fused, no x2]
    mgemm_glu<<<dim3(16, 64), blk, 0, stream>>>(
        out1b, w1b, w2b, w1_b, w2_b, hid, 2048, CDIM);
    // 5) out = hid @ w3b^T + w3_b (fp32 -> d_out)
    mgemm<0, true, false><<<dim3(8, 64), blk, 0, stream>>>(
        hid, w3b, w3_b, out, CDIM, nullptr, 0, 2048);
}

// Round 4
// 503.627 us; speedup vs baseline: 1.1190x; 1.1190x over previous
//
#include <hip/hip_runtime.h>
#include <hip/hip_bf16.h>
#include <math.h>

// ---------------------------------------------------------------------------
// Round 13. R12 regressed (563.6): mgemm_glu's 128x128 double-acc needed
// ~276 regs/thread -> 1 wave/SIMD (Occupancy 11.3%), MfmaUtil 15.5%.
// Fix-forward: fused GLU with 128x64 N-tile (grid 32x64):
//   acc1[4][2]+acc2[4][2] = 64 acc regs (~115 total) -> >=2 blocks/CU;
//   LDS 16KB; 4 gld16 + 16 MFMA per wave per K-step (same intensity as
//   proven mgemm). x2 roundtrip stays eliminated (~144MB HBM saved vs R11).
// attn / mgemm / mgemm_qkv unchanged (proven R11/R12).
// ---------------------------------------------------------------------------

#define SEQ     2048
#define BATCH   4
#define NH      16
#define CDIM    1024
#define MROWS   8192

typedef __bf16 bf16x8 __attribute__((ext_vector_type(8)));
typedef float  floatx4 __attribute__((ext_vector_type(4)));
typedef float  floatx16 __attribute__((ext_vector_type(16)));
typedef unsigned int u32;

__device__ __forceinline__ unsigned short f2bf(float f) {
    __bf16 h = (__bf16)f;                      // RNE, HW cvt on gfx950
    return __builtin_bit_cast(unsigned short, h);
}
__device__ __forceinline__ float fexp2(float x) {   // 2^x
    float r; asm("v_exp_f32 %0, %1" : "=v"(r) : "v"(x)); return r;
}
__device__ __forceinline__ floatx4 mfma16(bf16x8 a, bf16x8 b, floatx4 c) {
    return __builtin_amdgcn_mfma_f32_16x16x32_bf16(a, b, c, 0, 0, 0);
}
__device__ __forceinline__ floatx16 mfma32(bf16x8 a, bf16x8 b, floatx16 c) {
    return __builtin_amdgcn_mfma_f32_32x32x16_bf16(a, b, c, 0, 0, 0);
}
// async global->LDS, 16B/lane; LDS dest wave-uniform base + lane*16
__device__ __forceinline__ void gld16(void* lds, const void* g) {
    __builtin_amdgcn_global_load_lds(
        (const __attribute__((address_space(1))) u32*)g,
        (__attribute__((address_space(3))) u32*)lds, 16, 0, 0);
}

// ============================================================
// bf16 MFMA GEMM NT, m97-style gload_lds staging (PROVEN):
// C[m,n] = sum_k A[m,k]*B[n,k] (+bias)
// ============================================================
template <int OUTMODE, bool BIAS>
__global__ __launch_bounds__(256) void mgemm(
    const unsigned short* __restrict__ A,
    const unsigned short* __restrict__ B,
    const float* __restrict__ bias,
    void* __restrict__ C, int ldc,
    int K)
{
    __shared__ __align__(16) unsigned short As[128 * 32];
    __shared__ __align__(16) unsigned short Bs[128 * 32];

    const int tid  = threadIdx.x;
    const int lane = tid & 63;
    const int wave = tid >> 6;
    const int l16  = lane & 15;
    const int quad = lane >> 4;
    const int wm = (wave >> 1) * 64, wn = (wave & 1) * 64;
    const int bm = blockIdx.y, bn = blockIdx.x;

    const unsigned short* Ag = A + (size_t)(bm * 128) * K;
    const unsigned short* Bg = B + (size_t)(bn * 128) * K;

    // gload geometry: wave w call j -> LDS rows (w*2+j)*16..+15 (1KB/call)
    const int srow0 = wave * 32 + (lane >> 2);
    const int scol  = (lane & 3) * 8;
    unsigned short* lA0 = As + (wave * 2 + 0) * 512;
    unsigned short* lA1 = As + (wave * 2 + 1) * 512;
    unsigned short* lB0 = Bs + (wave * 2 + 0) * 512;
    unsigned short* lB1 = Bs + (wave * 2 + 1) * 512;
    const unsigned short* gA0 = Ag + (size_t)srow0 * K + scol;
    const unsigned short* gA1 = Ag + (size_t)(srow0 + 16) * K + scol;
    const unsigned short* gB0 = Bg + (size_t)srow0 * K + scol;
    const unsigned short* gB1 = Bg + (size_t)(srow0 + 16) * K + scol;

    floatx4 acc[4][4] = {};

    for (int kt = 0; kt < K; kt += 32) {
        __syncthreads();                 // prev tile's frag reads complete
        gld16(lA0, gA0 + kt);
        gld16(lA1, gA1 + kt);
        gld16(lB0, gB0 + kt);
        gld16(lB1, gB1 + kt);
        __syncthreads();                 // vmcnt drained -> tile ready

        bf16x8 af[4], bfr[4];
        #pragma unroll
        for (int mt = 0; mt < 4; ++mt)
            af[mt] = *(const bf16x8*)&As[(wm + mt * 16 + l16) * 32 + quad * 8];
        #pragma unroll
        for (int nt = 0; nt < 4; ++nt)
            bfr[nt] = *(const bf16x8*)&Bs[(wn + nt * 16 + l16) * 32 + quad * 8];
        #pragma unroll
        for (int mt = 0; mt < 4; ++mt)
            #pragma unroll
            for (int nt = 0; nt < 4; ++nt)
                acc[mt][nt] = mfma16(af[mt], bfr[nt], acc[mt][nt]);
    }

    #pragma unroll
    for (int nt = 0; nt < 4; ++nt) {
        const int gcol = bn * 128 + wn + nt * 16 + l16;
        const float bv = BIAS ? bias[gcol] : 0.0f;
        #pragma unroll
        for (int mt = 0; mt < 4; ++mt) {
            #pragma unroll
            for (int r = 0; r < 4; ++r) {
                const int grow = bm * 128 + wm + mt * 16 + quad * 4 + r;
                float v = acc[mt][nt][r] + bv;
                if (OUTMODE == 0)
                    ((float*)C)[(size_t)grow * ldc + gcol] = v;
                else
                    ((unsigned short*)C)[(size_t)grow * ldc + gcol] = f2bf(v);
            }
        }
    }
}

// ============================================================
// Fused SwiGLU GEMM, 128x64 N-tile (occupancy-fixed):
// hid[m,n] = silu(A@W1^T + b1) * (A@W2^T + b2)
// acc1[4][2]+acc2[4][2]=64 acc regs; LDS 16KB;
// 4 gld16 + 16 MFMA per wave per K-step.
// ============================================================
__global__ __launch_bounds__(256) void mgemm_glu(
    const unsigned short* __restrict__ A,
    const unsigned short* __restrict__ B1,
    const unsigned short* __restrict__ B2,
    const float* __restrict__ bias1,
    const float* __restrict__ bias2,
    unsigned short* __restrict__ C, int ldc,
    int K)
{
    __shared__ __align__(16) unsigned short As[128 * 32];
    __shared__ __align__(16) unsigned short B1s[64 * 32];
    __shared__ __align__(16) unsigned short B2s[64 * 32];

    const int tid  = threadIdx.x;
    const int lane = tid & 63;
    const int wave = tid >> 6;
    const int l16  = lane & 15;
    const int quad = lane >> 4;
    const int wm = (wave >> 1) * 64, wn = (wave & 1) * 32;
    const int bm = blockIdx.y, bn = blockIdx.x;

    const unsigned short* Ag  = A  + (size_t)(bm * 128) * K;
    const unsigned short* B1g = B1 + (size_t)(bn * 64) * K;
    const unsigned short* B2g = B2 + (size_t)(bn * 64) * K;

    // A: wave w stages rows w*32..+31 (2 calls); B1/B2: rows w*16..+15 (1 each)
    const int arow = wave * 32 + (lane >> 2);
    const int brow = wave * 16 + (lane >> 2);
    const int scol = (lane & 3) * 8;
    unsigned short* lA0  = As  + (wave * 2 + 0) * 512;
    unsigned short* lA1  = As  + (wave * 2 + 1) * 512;
    unsigned short* lB1w = B1s + wave * 512;
    unsigned short* lB2w = B2s + wave * 512;
    const unsigned short* gA0 = Ag  + (size_t)arow * K + scol;
    const unsigned short* gA1 = Ag  + (size_t)(arow + 16) * K + scol;
    const unsigned short* gB1 = B1g + (size_t)brow * K + scol;
    const unsigned short* gB2 = B2g + (size_t)brow * K + scol;

    floatx4 acc1[4][2] = {};
    floatx4 acc2[4][2] = {};

    for (int kt = 0; kt < K; kt += 32) {
        __syncthreads();
        gld16(lA0,  gA0 + kt);
        gld16(lA1,  gA1 + kt);
        gld16(lB1w, gB1 + kt);
        gld16(lB2w, gB2 + kt);
        __syncthreads();

        bf16x8 af[4], b1f[2], b2f[2];
        #pragma unroll
        for (int mt = 0; mt < 4; ++mt)
            af[mt] = *(const bf16x8*)&As[(wm + mt * 16 + l16) * 32 + quad * 8];
        #pragma unroll
        for (int nt = 0; nt < 2; ++nt) {
            b1f[nt] = *(const bf16x8*)&B1s[(wn + nt * 16 + l16) * 32 + quad * 8];
            b2f[nt] = *(const bf16x8*)&B2s[(wn + nt * 16 + l16) * 32 + quad * 8];
        }
        #pragma unroll
        for (int mt = 0; mt < 4; ++mt)
            #pragma unroll
            for (int nt = 0; nt < 2; ++nt) {
                acc1[mt][nt] = mfma16(af[mt], b1f[nt], acc1[mt][nt]);
                acc2[mt][nt] = mfma16(af[mt], b2f[nt], acc2[mt][nt]);
            }
    }

    #pragma unroll
    for (int nt = 0; nt < 2; ++nt) {
        const int gcol = bn * 64 + wn + nt * 16 + l16;
        const float b1 = bias1[gcol];
        const float b2 = bias2[gcol];
        #pragma unroll
        for (int mt = 0; mt < 4; ++mt) {
            #pragma unroll
            for (int r = 0; r < 4; ++r) {
                const int grow = bm * 128 + wm + mt * 16 + quad * 4 + r;
                const float x1 = acc1[mt][nt][r] + b1;
                const float x2 = acc2[mt][nt][r] + b2;
                const float v = (x1 / (1.0f + expf(-x1))) * x2;
                C[(size_t)grow * ldc + gcol] = f2bf(v);
            }
        }
    }
}

// ============================================================
// QKV GEMM (gload_lds staging), fused epilogues (PROVEN):
//  q/k: fp32 RoPE (table), q pre-scaled by 0.125*log2e, -> Qb/Kb [bh][n][64]
//  v:   LDS-transposed (reuses dead As) -> Vtb [bh][d][n], 16B stores
// ============================================================
__global__ __launch_bounds__(256) void mgemm_qkv(
    const unsigned short* __restrict__ A,
    const unsigned short* __restrict__ B,
    const float* __restrict__ tab,
    unsigned short* __restrict__ Qb,
    unsigned short* __restrict__ Kb,
    unsigned short* __restrict__ Vtb)
{
    __shared__ __align__(16) unsigned short As[128 * 32];
    __shared__ __align__(16) unsigned short Bs[128 * 32];

    const int tid  = threadIdx.x;
    const int lane = tid & 63;
    const int wave = tid >> 6;
    const int l16  = lane & 15;
    const int quad = lane >> 4;
    const int wm = (wave >> 1) * 64, wn = (wave & 1) * 64;
    const int bm = blockIdx.y, bn = blockIdx.x;
    const int K = CDIM;

    const unsigned short* Ag = A + (size_t)(bm * 128) * K;
    const unsigned short* Bg = B + (size_t)(bn * 128) * K;

    const int srow0 = wave * 32 + (lane >> 2);
    const int scol  = (lane & 3) * 8;
    unsigned short* lA0 = As + (wave * 2 + 0) * 512;
    unsigned short* lA1 = As + (wave * 2 + 1) * 512;
    unsigned short* lB0 = Bs + (wave * 2 + 0) * 512;
    unsigned short* lB1 = Bs + (wave * 2 + 1) * 512;
    const unsigned short* gA0 = Ag + (size_t)srow0 * K + scol;
    const unsigned short* gA1 = Ag + (size_t)(srow0 + 16) * K + scol;
    const unsigned short* gB0 = Bg + (size_t)srow0 * K + scol;
    const unsigned short* gB1 = Bg + (size_t)(srow0 + 16) * K + scol;

    floatx4 acc[4][4] = {};

    for (int kt = 0; kt < K; kt += 32) {
        __syncthreads();
        gld16(lA0, gA0 + kt);
        gld16(lA1, gA1 + kt);
        gld16(lB0, gB0 + kt);
        gld16(lB1, gB1 + kt);
        __syncthreads();

        bf16x8 af[4], bfr[4];
        #pragma unroll
        for (int mt = 0; mt < 4; ++mt)
            af[mt] = *(const bf16x8*)&As[(wm + mt * 16 + l16) * 32 + quad * 8];
        #pragma unroll
        for (int nt = 0; nt < 4; ++nt)
            bfr[nt] = *(const bf16x8*)&Bs[(wn + nt * 16 + l16) * 32 + quad * 8];
        #pragma unroll
        for (int mt = 0; mt < 4; ++mt)
            #pragma unroll
            for (int nt = 0; nt < 4; ++nt)
                acc[mt][nt] = mfma16(af[mt], bfr[nt], acc[mt][nt]);
    }

    // part is BLOCK-uniform: 128-col blocks never straddle a 1024 boundary.
    const int colbase0 = bn * 128;
    const int part = colbase0 >> 10;            // 0=q 1=k 2=v

    if (part == 2) {
        // ---- V: transpose via LDS (As dead), write Vtb [bh][d][n] ----
        unsigned short* T = As;                 // 4 waves x 64d x 16n ushorts
        #pragma unroll
        for (int mt = 0; mt < 4; ++mt) {
            __syncthreads();
            #pragma unroll
            for (int nt = 0; nt < 4; ++nt) {
                ushort4 pk;
                pk.x = f2bf(acc[mt][nt][0]); pk.y = f2bf(acc[mt][nt][1]);
                pk.z = f2bf(acc[mt][nt][2]); pk.w = f2bf(acc[mt][nt][3]);
                *(ushort4*)&T[((wave * 64 + nt * 16 + l16) * 16) + quad * 4] = pk;
            }
            __syncthreads();
            // 256 threads: w2 = tid>>6 (wave-tile), d = tid&63; 32B per thread
            const int w2 = tid >> 6, d = tid & 63;
            const int nrow0 = bm * 128 + (w2 >> 1) * 64 + mt * 16;
            const int b = nrow0 >> 11, n0 = nrow0 & 2047;
            const int h2 = ((bn * 128 + (w2 & 1) * 64) & 1023) >> 6;
            unsigned short* dst = Vtb +
                ((size_t)(b * NH + h2) * 64 + d) * 2048 + n0;
            const int tb = (w2 * 64 + d) * 16;
            *(uint4*)dst       = *(const uint4*)&T[tb];
            *(uint4*)(dst + 8) = *(const uint4*)&T[tb + 8];
        }
    } else {
        // ---- q/k: fp32 RoPE; q scaled by 0.125*log2e (exp2 softmax) ----
        const float qscale = (part == 0) ? 0.125f * 1.44269504088896f : 1.0f;
        const int h = ((colbase0 + wn) & 1023) >> 6;
        #pragma unroll
        for (int mt = 0; mt < 4; ++mt) {
            #pragma unroll
            for (int r = 0; r < 4; ++r) {
                const int grow = bm * 128 + wm + mt * 16 + quad * 4 + r;
                const int b = grow >> 11, n = grow & 2047;
                unsigned short* dst =
                    (part == 0 ? Qb : Kb) + ((size_t)(b * NH + h) * 2048 + n) * 64;
                #pragma unroll
                for (int nt = 0; nt < 2; ++nt) {
                    const int i = nt * 16 + l16;          // 0..31
                    const float c  = tab[(n * 32 + i) * 2];
                    const float sn = tab[(n * 32 + i) * 2 + 1];
                    const float x1 = acc[mt][nt][r];
                    const float x2v = acc[mt][nt + 2][r];
                    dst[i]      = f2bf((x1 * c - x2v * sn) * qscale);
                    dst[i + 32] = f2bf((x2v * c + x1 * sn) * qscale);
                }
            }
        }
    }
}

// ============================================================
// MFMA flash attention v3.1 (unchanged from R11): 128-query blocks,
// 32x32x16 MFMA, P = exp2(S) with log2e folded into Q, T14 prefetch.
// ============================================================
__global__ __launch_bounds__(256) void attn_mfma(
    const unsigned short* __restrict__ Qb,
    const unsigned short* __restrict__ Kb,
    const unsigned short* __restrict__ Vtb,
    unsigned short* __restrict__ Ob)
{
    const int qt = blockIdx.x;        // 0..15
    const int bh = blockIdx.y;        // 0..63
    const int tid = threadIdx.x;
    const int lane = tid & 63, wave = tid >> 6;
    const int r32 = lane & 31, hi = lane >> 5;
    const int q0 = wave * 32;
    const int qrow = q0 + r32;        // this lane's query row in LDS

    __shared__ unsigned short QP[128][72];  // Q staging, then P [q][key]
    __shared__ unsigned short Ks[64][72];   // K tile [key][dim]
    __shared__ unsigned short Vs[64][72];   // V^T tile [dim][key]

    const unsigned short* Qg = Qb + ((size_t)bh * 2048 + qt * 128) * 64;
    const unsigned short* Kg = Kb + (size_t)bh * 2048 * 64;
    const unsigned short* Vg = Vtb + (size_t)bh * 64 * 2048;

    // stage Q tile 128x64
    #pragma unroll
    for (int rep = 0; rep < 4; ++rep) {
        const int c = tid + rep * 256;
        const int r = c >> 3, d0 = (c & 7) * 8;
        *(uint4*)&QP[r][d0] = *(const uint4*)(Qg + (size_t)r * 64 + d0);
    }

    // K/V staging slots for this thread (2 b128 each per tile)
    const int c0 = tid, c1 = tid + 256;
    const int kr0 = c0 >> 3, kd0 = (c0 & 7) * 8;
    const int kr1 = c1 >> 3, kd1 = (c1 & 7) * 8;

    // T14 prefetch tile 0 into regs
    uint4 ka0 = *(const uint4*)(Kg + (size_t)kr0 * 64 + kd0);
    uint4 ka1 = *(const uint4*)(Kg + (size_t)kr1 * 64 + kd1);
    uint4 va0 = *(const uint4*)(Vg + (size_t)kr0 * 2048 + kd0);
    uint4 va1 = *(const uint4*)(Vg + (size_t)kr1 * 2048 + kd1);

    __syncthreads();   // Q tile ready

    // Q B-frags (rows = wave's 32 queries), held for all iterations
    bf16x8 bq[4];
    #pragma unroll
    for (int f = 0; f < 4; ++f)
        bq[f] = *(const bf16x8*)&QP[qrow][f * 16 + hi * 8];

    floatx16 o0 = {}, o1 = {};      // O^T[d][q]: d-tiles 0..31 / 32..63
    float l_acc = 0.0f;

    for (int kt = 0; kt < 32; ++kt) {
        __syncthreads();   // prev tile's Ks/Vs frag reads complete
        *(uint4*)&Ks[kr0][kd0] = ka0;
        *(uint4*)&Ks[kr1][kd1] = ka1;
        *(uint4*)&Vs[kr0][kd0] = va0;
        *(uint4*)&Vs[kr1][kd1] = va1;
        if (kt + 1 < 32) {           // T14: issue next-tile loads now,
            const size_t nb = (size_t)(kt + 1) * 64;     // land during compute
            ka0 = *(const uint4*)(Kg + (nb + kr0) * 64 + kd0);
            ka1 = *(const uint4*)(Kg + (nb + kr1) * 64 + kd1);
            va0 = *(const uint4*)(Vg + (size_t)kr0 * 2048 + nb + kd0);
            va1 = *(const uint4*)(Vg + (size_t)kr1 * 2048 + nb + kd1);
        }
        __syncthreads();   // tile ready

        // ---- S^T (2 key subtiles of 32) + exp2 + P write + rowsum ----
        #pragma unroll
        for (int t = 0; t < 2; ++t) {
            floatx16 s = {};
            #pragma unroll
            for (int f = 0; f < 4; ++f) {
                const bf16x8 ak = *(const bf16x8*)&Ks[t * 32 + r32][f * 16 + hi * 8];
                s = mfma32(ak, bq[f], s);
            }
            float rs = 0.0f;
            #pragma unroll
            for (int g = 0; g < 4; ++g) {
                const float p0 = fexp2(s[4 * g + 0]);
                const float p1 = fexp2(s[4 * g + 1]);
                const float p2 = fexp2(s[4 * g + 2]);
                const float p3 = fexp2(s[4 * g + 3]);
                rs += (p0 + p1) + (p2 + p3);
                ushort4 pk;
                pk.x = f2bf(p0); pk.y = f2bf(p1); pk.z = f2bf(p2); pk.w = f2bf(p3);
                // key = t*32 + 8g + 4*hi + (0..3)
                *(ushort4*)&QP[qrow][t * 32 + 8 * g + 4 * hi] = pk;
            }
            l_acc += rs;
        }

        // ---- O^T += V^T P^T (same-wave LDS RAW: in-order DS pipe) ----
        bf16x8 bp[4];
        #pragma unroll
        for (int f = 0; f < 4; ++f)
            bp[f] = *(const bf16x8*)&QP[qrow][f * 16 + hi * 8];
        #pragma unroll
        for (int f = 0; f < 4; ++f) {
            const bf16x8 av0 = *(const bf16x8*)&Vs[r32][f * 16 + hi * 8];
            o0 = mfma32(av0, bp[f], o0);
            const bf16x8 av1 = *(const bf16x8*)&Vs[32 + r32][f * 16 + hi * 8];
            o1 = mfma32(av1, bp[f], o1);
        }
    }

    // epilogue: lane's query = q0 + r32; lanes l/l+32 hold disjoint key
    // halves of the same query -> one shfl to complete l.
    const float l_tot = l_acc + __shfl_xor(l_acc, 32);
    const float inv = 1.0f / l_tot;
    const int b = bh >> 4, h = bh & 15;
    unsigned short* orow = Ob +
        (size_t)(b * SEQ + qt * 128 + qrow) * CDIM + h * 64;
    #pragma unroll
    for (int u = 0; u < 2; ++u) {
        const floatx16 ov = u ? o1 : o0;
        #pragma unroll
        for (int g = 0; g < 4; ++g) {
            ushort4 pk;
            pk.x = f2bf(ov[4 * g + 0] * inv); pk.y = f2bf(ov[4 * g + 1] * inv);
            pk.z = f2bf(ov[4 * g + 2] * inv); pk.w = f2bf(ov[4 * g + 3] * inv);
            // d = u*32 + 8g + 4*hi + (0..3)
            *(ushort4*)(orow + u * 32 + 8 * g + 4 * hi) = pk;
        }
    }
}

// ============================================================
// fp32 -> bf16 converter; RoPE table (fp64 angles)
// ============================================================
__global__ __launch_bounds__(256) void cvt_bf16(
    const float* __restrict__ src, unsigned short* __restrict__ dst)
{
    const size_t i = ((size_t)blockIdx.x * 256 + threadIdx.x) * 4;
    const float4 f = *(const float4*)(src + i);
    ushort4 o; o.x = f2bf(f.x); o.y = f2bf(f.y); o.z = f2bf(f.z); o.w = f2bf(f.w);
    *(ushort4*)(dst + i) = o;
}

__global__ __launch_bounds__(256) void rope_table(float* __restrict__ tab)
{
    const int idx = blockIdx.x * 256 + threadIdx.x;   // < 65536
    const int i = idx & 31, n = idx >> 5;
    const double f = (double)n * pow(10000.0, -(double)(2 * i) / 64.0);
    tab[idx * 2]     = (float)cos(f);
    tab[idx * 2 + 1] = (float)sin(f);
}

// ============================================================
// kernel_launch
// ============================================================
extern "C" void kernel_launch(void* const* d_in, const int* in_sizes, int n_in,
                              void* d_out, int out_size, void* d_ws, size_t ws_size,
                              hipStream_t stream)
{
    const float* x      = (const float*)d_in[0];
    const float* qkv_w  = (const float*)d_in[1];
    const float* proj_w = (const float*)d_in[2];
    const float* proj_b = (const float*)d_in[3];
    const float* w1_w   = (const float*)d_in[4];
    const float* w1_b   = (const float*)d_in[5];
    const float* w2_w   = (const float*)d_in[6];
    const float* w2_b   = (const float*)d_in[7];
    const float* w3_w   = (const float*)d_in[8];
    const float* w3_b   = (const float*)d_in[9];
    float* out = (float*)d_out;

    char* ws = (char*)d_ws;
    unsigned short* Qb    = (unsigned short*)(ws);              // [0,16M)
    unsigned short* Kb    = (unsigned short*)(ws + 16777216);   // [16,32M)
    unsigned short* Vtb   = (unsigned short*)(ws + 33554432);   // [32,48M)
    unsigned short* Ob    = (unsigned short*)(ws + 50331648);   // [48,64M)
    unsigned short* out1b = (unsigned short*)(ws + 67108864);   // [64,80M)
    unsigned short* w1b   = (unsigned short*)(ws + 83886080);   // [80,84M)
    unsigned short* w2b   = (unsigned short*)(ws + 88080384);   // [84,88M)
    unsigned short* w3b   = (unsigned short*)(ws + 92274688);   // [88,92M)
    unsigned short* projb = (unsigned short*)(ws + 96468992);   // [92,94M)
    unsigned short* xb    = (unsigned short*)(ws + 98566144);   // [94,110M)
    unsigned short* wqkvb = (unsigned short*)(ws + 115343360);  // [110,116M)
    float*          tab   = (float*)(ws + 121634816);           // [116,116.5M)
    unsigned short* hid   = (unsigned short*)(ws);              // [0,32M) (x2 gone)

    const dim3 blk(256);

    cvt_bf16<<<dim3(8192), blk, 0, stream>>>(x, xb);
    cvt_bf16<<<dim3(3072), blk, 0, stream>>>(qkv_w, wqkvb);
    cvt_bf16<<<dim3(1024), blk, 0, stream>>>(proj_w, projb);
    cvt_bf16<<<dim3(2048), blk, 0, stream>>>(w1_w, w1b);
    cvt_bf16<<<dim3(2048), blk, 0, stream>>>(w2_w, w2b);
    cvt_bf16<<<dim3(2048), blk, 0, stream>>>(w3_w, w3b);
    rope_table<<<dim3(256), blk, 0, stream>>>(tab);

    // 1) QKV GEMM + fused rope/scale + coalesced transpose scatter
    mgemm_qkv<<<dim3(24, 64), blk, 0, stream>>>(xb, wqkvb, tab, Qb, Kb, Vtb);
    // 2) MFMA flash attention (128-query blocks) -> Ob bf16 [8192,1024]
    attn_mfma<<<dim3(SEQ / 128, BATCH * NH), blk, 0, stream>>>(Qb, Kb, Vtb, Ob);
    // 3) out1b = Ob @ projb^T + proj_b (bf16)
    mgemm<1, true><<<dim3(8, 64), blk, 0, stream>>>(
        Ob, projb, proj_b, out1b, CDIM, CDIM);
    // 4) hid = silu(out1b@w1^T + b1) * (out1b@w2^T + b2)  [fused, no x2]
    mgemm_glu<<<dim3(32, 64), blk, 0, stream>>>(
        out1b, w1b, w2b, w1_b, w2_b, hid, 2048, CDIM);
    // 5) out = hid @ w3b^T + w3_b (fp32 -> d_out)
    mgemm<0, true><<<dim3(8, 64), blk, 0, stream>>>(
        hid, w3b, w3_b, out, CDIM, 2048);
}

// Round 5
// 491.957 us; speedup vs baseline: 1.1456x; 1.0237x over previous
//
#include <hip/hip_runtime.h>
#include <hip/hip_bf16.h>
#include <math.h>

// ---------------------------------------------------------------------------
// Round 14. R13 measured 503.6us (best). attn top dispatch: 107us,
// MfmaUtil 27.4%, VALU 42.7%, FETCH 139MB (ideal 48MB).
// Changes (attn + prologue only; GEMMs proven, unchanged):
//  1) T12: P kept in registers. exp2 -> v_cvt_pk_bf16_f32 pairs ->
//     v_permlane32_swap_b32 (dst.hi<->src.lo, same lane&31) assembles PV
//     B-frags in-reg. Kills 8 ds_write_b64 + 4 ds_read_b128 + same-wave
//     RAW stall per wave-iter; PV interleaved per 32-key subtile.
//  2) T1: grid transposed to (64,16): same-bh blocks = same id mod 8 =
//     same XCD -> K/V L2-resident per XCD. FETCH should drop ~2x.
//  3) 6 cvt_bf16 launches -> 1 cvt_all (block-uniform segment if-chain).
// ---------------------------------------------------------------------------

#define SEQ     2048
#define BATCH   4
#define NH      16
#define CDIM    1024
#define MROWS   8192

typedef __bf16 bf16x8 __attribute__((ext_vector_type(8)));
typedef float  floatx4 __attribute__((ext_vector_type(4)));
typedef float  floatx16 __attribute__((ext_vector_type(16)));
typedef unsigned int u32;

__device__ __forceinline__ unsigned short f2bf(float f) {
    __bf16 h = (__bf16)f;                      // RNE, HW cvt on gfx950
    return __builtin_bit_cast(unsigned short, h);
}
__device__ __forceinline__ float fexp2(float x) {   // 2^x
    float r; asm("v_exp_f32 %0, %1" : "=v"(r) : "v"(x)); return r;
}
__device__ __forceinline__ u32 cvtpk(float lo, float hi) {  // 2xbf16 word
    u32 w; asm("v_cvt_pk_bf16_f32 %0, %1, %2" : "=v"(w) : "v"(lo), "v"(hi));
    return w;
}
__device__ __forceinline__ floatx4 mfma16(bf16x8 a, bf16x8 b, floatx4 c) {
    return __builtin_amdgcn_mfma_f32_16x16x32_bf16(a, b, c, 0, 0, 0);
}
__device__ __forceinline__ floatx16 mfma32(bf16x8 a, bf16x8 b, floatx16 c) {
    return __builtin_amdgcn_mfma_f32_32x32x16_bf16(a, b, c, 0, 0, 0);
}
// async global->LDS, 16B/lane; LDS dest wave-uniform base + lane*16
__device__ __forceinline__ void gld16(void* lds, const void* g) {
    __builtin_amdgcn_global_load_lds(
        (const __attribute__((address_space(1))) u32*)g,
        (__attribute__((address_space(3))) u32*)lds, 16, 0, 0);
}

// ============================================================
// bf16 MFMA GEMM NT, m97-style gload_lds staging (PROVEN):
// C[m,n] = sum_k A[m,k]*B[n,k] (+bias)
// ============================================================
template <int OUTMODE, bool BIAS>
__global__ __launch_bounds__(256) void mgemm(
    const unsigned short* __restrict__ A,
    const unsigned short* __restrict__ B,
    const float* __restrict__ bias,
    void* __restrict__ C, int ldc,
    int K)
{
    __shared__ __align__(16) unsigned short As[128 * 32];
    __shared__ __align__(16) unsigned short Bs[128 * 32];

    const int tid  = threadIdx.x;
    const int lane = tid & 63;
    const int wave = tid >> 6;
    const int l16  = lane & 15;
    const int quad = lane >> 4;
    const int wm = (wave >> 1) * 64, wn = (wave & 1) * 64;
    const int bm = blockIdx.y, bn = blockIdx.x;

    const unsigned short* Ag = A + (size_t)(bm * 128) * K;
    const unsigned short* Bg = B + (size_t)(bn * 128) * K;

    // gload geometry: wave w call j -> LDS rows (w*2+j)*16..+15 (1KB/call)
    const int srow0 = wave * 32 + (lane >> 2);
    const int scol  = (lane & 3) * 8;
    unsigned short* lA0 = As + (wave * 2 + 0) * 512;
    unsigned short* lA1 = As + (wave * 2 + 1) * 512;
    unsigned short* lB0 = Bs + (wave * 2 + 0) * 512;
    unsigned short* lB1 = Bs + (wave * 2 + 1) * 512;
    const unsigned short* gA0 = Ag + (size_t)srow0 * K + scol;
    const unsigned short* gA1 = Ag + (size_t)(srow0 + 16) * K + scol;
    const unsigned short* gB0 = Bg + (size_t)srow0 * K + scol;
    const unsigned short* gB1 = Bg + (size_t)(srow0 + 16) * K + scol;

    floatx4 acc[4][4] = {};

    for (int kt = 0; kt < K; kt += 32) {
        __syncthreads();                 // prev tile's frag reads complete
        gld16(lA0, gA0 + kt);
        gld16(lA1, gA1 + kt);
        gld16(lB0, gB0 + kt);
        gld16(lB1, gB1 + kt);
        __syncthreads();                 // vmcnt drained -> tile ready

        bf16x8 af[4], bfr[4];
        #pragma unroll
        for (int mt = 0; mt < 4; ++mt)
            af[mt] = *(const bf16x8*)&As[(wm + mt * 16 + l16) * 32 + quad * 8];
        #pragma unroll
        for (int nt = 0; nt < 4; ++nt)
            bfr[nt] = *(const bf16x8*)&Bs[(wn + nt * 16 + l16) * 32 + quad * 8];
        #pragma unroll
        for (int mt = 0; mt < 4; ++mt)
            #pragma unroll
            for (int nt = 0; nt < 4; ++nt)
                acc[mt][nt] = mfma16(af[mt], bfr[nt], acc[mt][nt]);
    }

    #pragma unroll
    for (int nt = 0; nt < 4; ++nt) {
        const int gcol = bn * 128 + wn + nt * 16 + l16;
        const float bv = BIAS ? bias[gcol] : 0.0f;
        #pragma unroll
        for (int mt = 0; mt < 4; ++mt) {
            #pragma unroll
            for (int r = 0; r < 4; ++r) {
                const int grow = bm * 128 + wm + mt * 16 + quad * 4 + r;
                float v = acc[mt][nt][r] + bv;
                if (OUTMODE == 0)
                    ((float*)C)[(size_t)grow * ldc + gcol] = v;
                else
                    ((unsigned short*)C)[(size_t)grow * ldc + gcol] = f2bf(v);
            }
        }
    }
}

// ============================================================
// Fused SwiGLU GEMM, 128x64 N-tile (PROVEN R13):
// hid[m,n] = silu(A@W1^T + b1) * (A@W2^T + b2)
// ============================================================
__global__ __launch_bounds__(256) void mgemm_glu(
    const unsigned short* __restrict__ A,
    const unsigned short* __restrict__ B1,
    const unsigned short* __restrict__ B2,
    const float* __restrict__ bias1,
    const float* __restrict__ bias2,
    unsigned short* __restrict__ C, int ldc,
    int K)
{
    __shared__ __align__(16) unsigned short As[128 * 32];
    __shared__ __align__(16) unsigned short B1s[64 * 32];
    __shared__ __align__(16) unsigned short B2s[64 * 32];

    const int tid  = threadIdx.x;
    const int lane = tid & 63;
    const int wave = tid >> 6;
    const int l16  = lane & 15;
    const int quad = lane >> 4;
    const int wm = (wave >> 1) * 64, wn = (wave & 1) * 32;
    const int bm = blockIdx.y, bn = blockIdx.x;

    const unsigned short* Ag  = A  + (size_t)(bm * 128) * K;
    const unsigned short* B1g = B1 + (size_t)(bn * 64) * K;
    const unsigned short* B2g = B2 + (size_t)(bn * 64) * K;

    const int arow = wave * 32 + (lane >> 2);
    const int brow = wave * 16 + (lane >> 2);
    const int scol = (lane & 3) * 8;
    unsigned short* lA0  = As  + (wave * 2 + 0) * 512;
    unsigned short* lA1  = As  + (wave * 2 + 1) * 512;
    unsigned short* lB1w = B1s + wave * 512;
    unsigned short* lB2w = B2s + wave * 512;
    const unsigned short* gA0 = Ag  + (size_t)arow * K + scol;
    const unsigned short* gA1 = Ag  + (size_t)(arow + 16) * K + scol;
    const unsigned short* gB1 = B1g + (size_t)brow * K + scol;
    const unsigned short* gB2 = B2g + (size_t)brow * K + scol;

    floatx4 acc1[4][2] = {};
    floatx4 acc2[4][2] = {};

    for (int kt = 0; kt < K; kt += 32) {
        __syncthreads();
        gld16(lA0,  gA0 + kt);
        gld16(lA1,  gA1 + kt);
        gld16(lB1w, gB1 + kt);
        gld16(lB2w, gB2 + kt);
        __syncthreads();

        bf16x8 af[4], b1f[2], b2f[2];
        #pragma unroll
        for (int mt = 0; mt < 4; ++mt)
            af[mt] = *(const bf16x8*)&As[(wm + mt * 16 + l16) * 32 + quad * 8];
        #pragma unroll
        for (int nt = 0; nt < 2; ++nt) {
            b1f[nt] = *(const bf16x8*)&B1s[(wn + nt * 16 + l16) * 32 + quad * 8];
            b2f[nt] = *(const bf16x8*)&B2s[(wn + nt * 16 + l16) * 32 + quad * 8];
        }
        #pragma unroll
        for (int mt = 0; mt < 4; ++mt)
            #pragma unroll
            for (int nt = 0; nt < 2; ++nt) {
                acc1[mt][nt] = mfma16(af[mt], b1f[nt], acc1[mt][nt]);
                acc2[mt][nt] = mfma16(af[mt], b2f[nt], acc2[mt][nt]);
            }
    }

    #pragma unroll
    for (int nt = 0; nt < 2; ++nt) {
        const int gcol = bn * 64 + wn + nt * 16 + l16;
        const float b1 = bias1[gcol];
        const float b2 = bias2[gcol];
        #pragma unroll
        for (int mt = 0; mt < 4; ++mt) {
            #pragma unroll
            for (int r = 0; r < 4; ++r) {
                const int grow = bm * 128 + wm + mt * 16 + quad * 4 + r;
                const float x1 = acc1[mt][nt][r] + b1;
                const float x2 = acc2[mt][nt][r] + b2;
                const float v = (x1 / (1.0f + expf(-x1))) * x2;
                C[(size_t)grow * ldc + gcol] = f2bf(v);
            }
        }
    }
}

// ============================================================
// QKV GEMM (gload_lds staging), fused epilogues (PROVEN):
//  q/k: fp32 RoPE (table), q pre-scaled by 0.125*log2e, -> Qb/Kb [bh][n][64]
//  v:   LDS-transposed (reuses dead As) -> Vtb [bh][d][n], 16B stores
// ============================================================
__global__ __launch_bounds__(256) void mgemm_qkv(
    const unsigned short* __restrict__ A,
    const unsigned short* __restrict__ B,
    const float* __restrict__ tab,
    unsigned short* __restrict__ Qb,
    unsigned short* __restrict__ Kb,
    unsigned short* __restrict__ Vtb)
{
    __shared__ __align__(16) unsigned short As[128 * 32];
    __shared__ __align__(16) unsigned short Bs[128 * 32];

    const int tid  = threadIdx.x;
    const int lane = tid & 63;
    const int wave = tid >> 6;
    const int l16  = lane & 15;
    const int quad = lane >> 4;
    const int wm = (wave >> 1) * 64, wn = (wave & 1) * 64;
    const int bm = blockIdx.y, bn = blockIdx.x;
    const int K = CDIM;

    const unsigned short* Ag = A + (size_t)(bm * 128) * K;
    const unsigned short* Bg = B + (size_t)(bn * 128) * K;

    const int srow0 = wave * 32 + (lane >> 2);
    const int scol  = (lane & 3) * 8;
    unsigned short* lA0 = As + (wave * 2 + 0) * 512;
    unsigned short* lA1 = As + (wave * 2 + 1) * 512;
    unsigned short* lB0 = Bs + (wave * 2 + 0) * 512;
    unsigned short* lB1 = Bs + (wave * 2 + 1) * 512;
    const unsigned short* gA0 = Ag + (size_t)srow0 * K + scol;
    const unsigned short* gA1 = Ag + (size_t)(srow0 + 16) * K + scol;
    const unsigned short* gB0 = Bg + (size_t)srow0 * K + scol;
    const unsigned short* gB1 = Bg + (size_t)(srow0 + 16) * K + scol;

    floatx4 acc[4][4] = {};

    for (int kt = 0; kt < K; kt += 32) {
        __syncthreads();
        gld16(lA0, gA0 + kt);
        gld16(lA1, gA1 + kt);
        gld16(lB0, gB0 + kt);
        gld16(lB1, gB1 + kt);
        __syncthreads();

        bf16x8 af[4], bfr[4];
        #pragma unroll
        for (int mt = 0; mt < 4; ++mt)
            af[mt] = *(const bf16x8*)&As[(wm + mt * 16 + l16) * 32 + quad * 8];
        #pragma unroll
        for (int nt = 0; nt < 4; ++nt)
            bfr[nt] = *(const bf16x8*)&Bs[(wn + nt * 16 + l16) * 32 + quad * 8];
        #pragma unroll
        for (int mt = 0; mt < 4; ++mt)
            #pragma unroll
            for (int nt = 0; nt < 4; ++nt)
                acc[mt][nt] = mfma16(af[mt], bfr[nt], acc[mt][nt]);
    }

    // part is BLOCK-uniform: 128-col blocks never straddle a 1024 boundary.
    const int colbase0 = bn * 128;
    const int part = colbase0 >> 10;            // 0=q 1=k 2=v

    if (part == 2) {
        // ---- V: transpose via LDS (As dead), write Vtb [bh][d][n] ----
        unsigned short* T = As;                 // 4 waves x 64d x 16n ushorts
        #pragma unroll
        for (int mt = 0; mt < 4; ++mt) {
            __syncthreads();
            #pragma unroll
            for (int nt = 0; nt < 4; ++nt) {
                ushort4 pk;
                pk.x = f2bf(acc[mt][nt][0]); pk.y = f2bf(acc[mt][nt][1]);
                pk.z = f2bf(acc[mt][nt][2]); pk.w = f2bf(acc[mt][nt][3]);
                *(ushort4*)&T[((wave * 64 + nt * 16 + l16) * 16) + quad * 4] = pk;
            }
            __syncthreads();
            // 256 threads: w2 = tid>>6 (wave-tile), d = tid&63; 32B per thread
            const int w2 = tid >> 6, d = tid & 63;
            const int nrow0 = bm * 128 + (w2 >> 1) * 64 + mt * 16;
            const int b = nrow0 >> 11, n0 = nrow0 & 2047;
            const int h2 = ((bn * 128 + (w2 & 1) * 64) & 1023) >> 6;
            unsigned short* dst = Vtb +
                ((size_t)(b * NH + h2) * 64 + d) * 2048 + n0;
            const int tb = (w2 * 64 + d) * 16;
            *(uint4*)dst       = *(const uint4*)&T[tb];
            *(uint4*)(dst + 8) = *(const uint4*)&T[tb + 8];
        }
    } else {
        // ---- q/k: fp32 RoPE; q scaled by 0.125*log2e (exp2 softmax) ----
        const float qscale = (part == 0) ? 0.125f * 1.44269504088896f : 1.0f;
        const int h = ((colbase0 + wn) & 1023) >> 6;
        #pragma unroll
        for (int mt = 0; mt < 4; ++mt) {
            #pragma unroll
            for (int r = 0; r < 4; ++r) {
                const int grow = bm * 128 + wm + mt * 16 + quad * 4 + r;
                const int b = grow >> 11, n = grow & 2047;
                unsigned short* dst =
                    (part == 0 ? Qb : Kb) + ((size_t)(b * NH + h) * 2048 + n) * 64;
                #pragma unroll
                for (int nt = 0; nt < 2; ++nt) {
                    const int i = nt * 16 + l16;          // 0..31
                    const float c  = tab[(n * 32 + i) * 2];
                    const float sn = tab[(n * 32 + i) * 2 + 1];
                    const float x1 = acc[mt][nt][r];
                    const float x2v = acc[mt][nt + 2][r];
                    dst[i]      = f2bf((x1 * c - x2v * sn) * qscale);
                    dst[i + 32] = f2bf((x2v * c + x1 * sn) * qscale);
                }
            }
        }
    }
}

// ============================================================
// MFMA flash attention v4: 128q blocks, 32x32x16, P in registers.
// S^T lane layout: P[q=lane&31][key=t*32+(r&3)+8*(r>>2)+4*hi].
// PV B-frag f needs P[q=l&31][f*16+hi*8+0..7]: built by
// cvt_pk pairs + v_permlane32_swap_b32 (dst.hi <-> src.lo; lane&31
// preserved). No P LDS roundtrip. Grid (bh, qt) for co-XCD K/V reuse.
// ============================================================
__global__ __launch_bounds__(256) void attn_mfma(
    const unsigned short* __restrict__ Qb,
    const unsigned short* __restrict__ Kb,
    const unsigned short* __restrict__ Vtb,
    unsigned short* __restrict__ Ob)
{
    const int bh = blockIdx.x;        // 0..63  (x-major: same-bh -> same XCD)
    const int qt = blockIdx.y;        // 0..15
    const int tid = threadIdx.x;
    const int lane = tid & 63, wave = tid >> 6;
    const int r32 = lane & 31, hi = lane >> 5;
    const int qrow = wave * 32 + r32; // this lane's query row in LDS

    __shared__ unsigned short QP[128][72];  // Q staging (held all iters)
    __shared__ unsigned short Ks[64][72];   // K tile [key][dim]
    __shared__ unsigned short Vs[64][72];   // V^T tile [dim][key]

    const unsigned short* Qg = Qb + ((size_t)bh * 2048 + qt * 128) * 64;
    const unsigned short* Kg = Kb + (size_t)bh * 2048 * 64;
    const unsigned short* Vg = Vtb + (size_t)bh * 64 * 2048;

    // stage Q tile 128x64
    #pragma unroll
    for (int rep = 0; rep < 4; ++rep) {
        const int c = tid + rep * 256;
        const int r = c >> 3, d0 = (c & 7) * 8;
        *(uint4*)&QP[r][d0] = *(const uint4*)(Qg + (size_t)r * 64 + d0);
    }

    // K/V staging slots for this thread (2 b128 each per tile)
    const int c0 = tid, c1 = tid + 256;
    const int kr0 = c0 >> 3, kd0 = (c0 & 7) * 8;
    const int kr1 = c1 >> 3, kd1 = (c1 & 7) * 8;

    // T14 prefetch tile 0 into regs
    uint4 ka0 = *(const uint4*)(Kg + (size_t)kr0 * 64 + kd0);
    uint4 ka1 = *(const uint4*)(Kg + (size_t)kr1 * 64 + kd1);
    uint4 va0 = *(const uint4*)(Vg + (size_t)kr0 * 2048 + kd0);
    uint4 va1 = *(const uint4*)(Vg + (size_t)kr1 * 2048 + kd1);

    __syncthreads();   // Q tile ready

    // Q B-frags (rows = wave's 32 queries), held for all iterations
    bf16x8 bq[4];
    #pragma unroll
    for (int f = 0; f < 4; ++f)
        bq[f] = *(const bf16x8*)&QP[qrow][f * 16 + hi * 8];

    floatx16 o0 = {}, o1 = {};      // O^T[d][q]: d-tiles 0..31 / 32..63
    float l_acc = 0.0f;

    for (int kt = 0; kt < 32; ++kt) {
        __syncthreads();   // prev tile's Ks/Vs frag reads complete
        *(uint4*)&Ks[kr0][kd0] = ka0;
        *(uint4*)&Ks[kr1][kd1] = ka1;
        *(uint4*)&Vs[kr0][kd0] = va0;
        *(uint4*)&Vs[kr1][kd1] = va1;
        if (kt + 1 < 32) {           // T14: issue next-tile loads now,
            const size_t nb = (size_t)(kt + 1) * 64;     // land during compute
            ka0 = *(const uint4*)(Kg + (nb + kr0) * 64 + kd0);
            ka1 = *(const uint4*)(Kg + (nb + kr1) * 64 + kd1);
            va0 = *(const uint4*)(Vg + (size_t)kr0 * 2048 + nb + kd0);
            va1 = *(const uint4*)(Vg + (size_t)kr1 * 2048 + nb + kd1);
        }
        __syncthreads();   // tile ready

        // ---- per 32-key subtile: S^T -> exp2 -> in-reg P -> PV ----
        #pragma unroll
        for (int t = 0; t < 2; ++t) {
            floatx16 s = {};
            #pragma unroll
            for (int f = 0; f < 4; ++f) {
                const bf16x8 ak = *(const bf16x8*)&Ks[t * 32 + r32][f * 16 + hi * 8];
                s = mfma32(ak, bq[f], s);
            }
            // p = exp2(s); rowsum
            float p[16];
            float rs = 0.0f;
            #pragma unroll
            for (int g = 0; g < 16; ++g) { p[g] = fexp2(s[g]); rs += p[g]; }
            l_acc += rs;
            // pack to bf16 words and swap halves across hi:
            // (w0,w2)=swap(pk(p0,p1),pk(p4,p5)); (w1,w3)=swap(pk(p2,p3),pk(p6,p7))
            // (w4,w6)=swap(pk(p8,p9),pk(p12,p13)); (w5,w7)=swap(pk(p10,p11),pk(p14,p15))
            u32 w0 = cvtpk(p[0], p[1]),   w2 = cvtpk(p[4], p[5]);
            u32 w1 = cvtpk(p[2], p[3]),   w3 = cvtpk(p[6], p[7]);
            u32 w4 = cvtpk(p[8], p[9]),   w6 = cvtpk(p[12], p[13]);
            u32 w5 = cvtpk(p[10], p[11]), w7 = cvtpk(p[14], p[15]);
            asm("v_permlane32_swap_b32 %0, %1" : "+v"(w0), "+v"(w2));
            asm("v_permlane32_swap_b32 %0, %1" : "+v"(w1), "+v"(w3));
            asm("v_permlane32_swap_b32 %0, %1" : "+v"(w4), "+v"(w6));
            asm("v_permlane32_swap_b32 %0, %1" : "+v"(w5), "+v"(w7));
            uint4 u0; u0.x = w0; u0.y = w1; u0.z = w2; u0.w = w3;
            uint4 u1; u1.x = w4; u1.y = w5; u1.z = w6; u1.w = w7;
            const bf16x8 bp0 = __builtin_bit_cast(bf16x8, u0);  // keys t*32 + slot0
            const bf16x8 bp1 = __builtin_bit_cast(bf16x8, u1);  // keys t*32 + slot1
            // PV for this subtile's two 16-key slots (f = 2t, 2t+1)
            {
                const int f0 = 2 * t, f1 = 2 * t + 1;
                const bf16x8 av00 = *(const bf16x8*)&Vs[r32][f0 * 16 + hi * 8];
                const bf16x8 av01 = *(const bf16x8*)&Vs[32 + r32][f0 * 16 + hi * 8];
                o0 = mfma32(av00, bp0, o0);
                o1 = mfma32(av01, bp0, o1);
                const bf16x8 av10 = *(const bf16x8*)&Vs[r32][f1 * 16 + hi * 8];
                const bf16x8 av11 = *(const bf16x8*)&Vs[32 + r32][f1 * 16 + hi * 8];
                o0 = mfma32(av10, bp1, o0);
                o1 = mfma32(av11, bp1, o1);
            }
        }
    }

    // epilogue: lane's query = wave*32 + r32; lanes l/l+32 hold disjoint key
    // halves of the same query -> one shfl to complete l.
    const float l_tot = l_acc + __shfl_xor(l_acc, 32);
    const float inv = 1.0f / l_tot;
    const int b = bh >> 4, h = bh & 15;
    unsigned short* orow = Ob +
        (size_t)(b * SEQ + qt * 128 + qrow) * CDIM + h * 64;
    #pragma unroll
    for (int u = 0; u < 2; ++u) {
        const floatx16 ov = u ? o1 : o0;
        #pragma unroll
        for (int g = 0; g < 4; ++g) {
            ushort4 pk;
            pk.x = f2bf(ov[4 * g + 0] * inv); pk.y = f2bf(ov[4 * g + 1] * inv);
            pk.z = f2bf(ov[4 * g + 2] * inv); pk.w = f2bf(ov[4 * g + 3] * inv);
            // d = u*32 + 8g + 4*hi + (0..3)
            *(ushort4*)(orow + u * 32 + 8 * g + 4 * hi) = pk;
        }
    }
}

// ============================================================
// One-shot fp32 -> bf16 for all six tensors (block-uniform segments);
// RoPE table (fp64 angles)
// ============================================================
__global__ __launch_bounds__(256) void cvt_all(
    const float* __restrict__ x,    const float* __restrict__ qkv,
    const float* __restrict__ proj, const float* __restrict__ w1,
    const float* __restrict__ w2,   const float* __restrict__ w3,
    unsigned short* __restrict__ xb,    unsigned short* __restrict__ qkvb,
    unsigned short* __restrict__ projb, unsigned short* __restrict__ w1b,
    unsigned short* __restrict__ w2b,   unsigned short* __restrict__ w3b)
{
    const size_t i = ((size_t)blockIdx.x * 256 + threadIdx.x) * 4;
    const float* src; unsigned short* dst; size_t off;
    if      (i <  8388608) { src = x;    dst = xb;    off = 0; }
    else if (i < 11534336) { src = qkv;  dst = qkvb;  off = 8388608; }
    else if (i < 12582912) { src = proj; dst = projb; off = 11534336; }
    else if (i < 14680064) { src = w1;   dst = w1b;   off = 12582912; }
    else if (i < 16777216) { src = w2;   dst = w2b;   off = 14680064; }
    else                   { src = w3;   dst = w3b;   off = 16777216; }
    const size_t j = i - off;
    const float4 f = *(const float4*)(src + j);
    ushort4 o; o.x = f2bf(f.x); o.y = f2bf(f.y); o.z = f2bf(f.z); o.w = f2bf(f.w);
    *(ushort4*)(dst + j) = o;
}

__global__ __launch_bounds__(256) void rope_table(float* __restrict__ tab)
{
    const int idx = blockIdx.x * 256 + threadIdx.x;   // < 65536
    const int i = idx & 31, n = idx >> 5;
    const double f = (double)n * pow(10000.0, -(double)(2 * i) / 64.0);
    tab[idx * 2]     = (float)cos(f);
    tab[idx * 2 + 1] = (float)sin(f);
}

// ============================================================
// kernel_launch
// ============================================================
extern "C" void kernel_launch(void* const* d_in, const int* in_sizes, int n_in,
                              void* d_out, int out_size, void* d_ws, size_t ws_size,
                              hipStream_t stream)
{
    const float* x      = (const float*)d_in[0];
    const float* qkv_w  = (const float*)d_in[1];
    const float* proj_w = (const float*)d_in[2];
    const float* proj_b = (const float*)d_in[3];
    const float* w1_w   = (const float*)d_in[4];
    const float* w1_b   = (const float*)d_in[5];
    const float* w2_w   = (const float*)d_in[6];
    const float* w2_b   = (const float*)d_in[7];
    const float* w3_w   = (const float*)d_in[8];
    const float* w3_b   = (const float*)d_in[9];
    float* out = (float*)d_out;

    char* ws = (char*)d_ws;
    unsigned short* Qb    = (unsigned short*)(ws);              // [0,16M)
    unsigned short* Kb    = (unsigned short*)(ws + 16777216);   // [16,32M)
    unsigned short* Vtb   = (unsigned short*)(ws + 33554432);   // [32,48M)
    unsigned short* Ob    = (unsigned short*)(ws + 50331648);   // [48,64M)
    unsigned short* out1b = (unsigned short*)(ws + 67108864);   // [64,80M)
    unsigned short* w1b   = (unsigned short*)(ws + 83886080);   // [80,84M)
    unsigned short* w2b   = (unsigned short*)(ws + 88080384);   // [84,88M)
    unsigned short* w3b   = (unsigned short*)(ws + 92274688);   // [88,92M)
    unsigned short* projb = (unsigned short*)(ws + 96468992);   // [92,94M)
    unsigned short* xb    = (unsigned short*)(ws + 98566144);   // [94,110M)
    unsigned short* wqkvb = (unsigned short*)(ws + 115343360);  // [110,116M)
    float*          tab   = (float*)(ws + 121634816);           // [116,116.5M)
    unsigned short* hid   = (unsigned short*)(ws);              // [0,32M)

    const dim3 blk(256);

    // all fp32->bf16 conversions in one dispatch (18874368 elems / 1024)
    cvt_all<<<dim3(18432), blk, 0, stream>>>(
        x, qkv_w, proj_w, w1_w, w2_w, w3_w,
        xb, wqkvb, projb, w1b, w2b, w3b);
    rope_table<<<dim3(256), blk, 0, stream>>>(tab);

    // 1) QKV GEMM + fused rope/scale + coalesced transpose scatter
    mgemm_qkv<<<dim3(24, 64), blk, 0, stream>>>(xb, wqkvb, tab, Qb, Kb, Vtb);
    // 2) MFMA flash attention; grid (bh, qt) -> same-bh blocks co-XCD
    attn_mfma<<<dim3(BATCH * NH, SEQ / 128), blk, 0, stream>>>(Qb, Kb, Vtb, Ob);
    // 3) out1b = Ob @ projb^T + proj_b (bf16)
    mgemm<1, true><<<dim3(8, 64), blk, 0, stream>>>(
        Ob, projb, proj_b, out1b, CDIM, CDIM);
    // 4) hid = silu(out1b@w1^T + b1) * (out1b@w2^T + b2)  [fused, no x2]
    mgemm_glu<<<dim3(32, 64), blk, 0, stream>>>(
        out1b, w1b, w2b, w1_b, w2_b, hid, 2048, CDIM);
    // 5) out = hid @ w3b^T + w3_b (fp32 -> d_out)
    mgemm<0, true><<<dim3(8, 64), blk, 0, stream>>>(
        hid, w3b, w3_b, out, CDIM, 2048);
}

// Round 6
// 479.889 us; speedup vs baseline: 1.1744x; 1.0251x over previous
//
#include <hip/hip_runtime.h>
#include <hip/hip_bf16.h>
#include <math.h>

// ---------------------------------------------------------------------------
// Round 15. R14 measured 492.0us (best). mgemm_glu top: 104.7us,
// VALU 54% vs Mfma 28% -> epilogue libm expf + fp32 div dominates VALU.
// Changes (all GEMM kernels; attn/cvt proven, unchanged):
//  1) glu epilogue: fast silu = x * v_rcp_f32(1 + v_exp_f32(-x*log2e)).
//     ~1000 -> ~80 VALU cyc/thread.
//  2) T3-min 2-phase pipeline in mgemm/mgemm_glu/mgemm_qkv: double-buffer
//     LDS (32KB), issue next tile's gld16 BEFORE current ds_read+MFMA,
//     then inline-asm vmcnt(0) + RAW s_barrier (no __syncthreads drain).
//     Loads land under the MFMA phase (m230/m248: 2ph-prefetch ~= 92% of
//     8-phase). sched_barrier(0) after barrier pins ordering.
// ---------------------------------------------------------------------------

#define SEQ     2048
#define BATCH   4
#define NH      16
#define CDIM    1024
#define MROWS   8192

typedef __bf16 bf16x8 __attribute__((ext_vector_type(8)));
typedef float  floatx4 __attribute__((ext_vector_type(4)));
typedef float  floatx16 __attribute__((ext_vector_type(16)));
typedef unsigned int u32;

__device__ __forceinline__ unsigned short f2bf(float f) {
    __bf16 h = (__bf16)f;                      // RNE, HW cvt on gfx950
    return __builtin_bit_cast(unsigned short, h);
}
__device__ __forceinline__ float fexp2(float x) {   // 2^x
    float r; asm("v_exp_f32 %0, %1" : "=v"(r) : "v"(x)); return r;
}
__device__ __forceinline__ float frcp(float x) {    // ~1ulp 1/x
    float r; asm("v_rcp_f32 %0, %1" : "=v"(r) : "v"(x)); return r;
}
__device__ __forceinline__ u32 cvtpk(float lo, float hi) {  // 2xbf16 word
    u32 w; asm("v_cvt_pk_bf16_f32 %0, %1, %2" : "=v"(w) : "v"(lo), "v"(hi));
    return w;
}
__device__ __forceinline__ floatx4 mfma16(bf16x8 a, bf16x8 b, floatx4 c) {
    return __builtin_amdgcn_mfma_f32_16x16x32_bf16(a, b, c, 0, 0, 0);
}
__device__ __forceinline__ floatx16 mfma32(bf16x8 a, bf16x8 b, floatx16 c) {
    return __builtin_amdgcn_mfma_f32_32x32x16_bf16(a, b, c, 0, 0, 0);
}
// async global->LDS, 16B/lane; LDS dest wave-uniform base + lane*16
__device__ __forceinline__ void gld16(void* lds, const void* g) {
    __builtin_amdgcn_global_load_lds(
        (const __attribute__((address_space(1))) u32*)g,
        (__attribute__((address_space(3))) u32*)lds, 16, 0, 0);
}
// counted-wait + raw barrier (no compiler vmcnt(0) drain)
__device__ __forceinline__ void wait_vm0_barrier() {
    asm volatile("s_waitcnt vmcnt(0)" ::: "memory");
    __builtin_amdgcn_s_barrier();
    __builtin_amdgcn_sched_barrier(0);
}
__device__ __forceinline__ void raw_barrier() {
    __builtin_amdgcn_s_barrier();
    __builtin_amdgcn_sched_barrier(0);
}

// ============================================================
// bf16 MFMA GEMM NT, 2-phase prefetch pipeline:
// C[m,n] = sum_k A[m,k]*B[n,k] (+bias)
// ============================================================
template <int OUTMODE, bool BIAS>
__global__ __launch_bounds__(256) void mgemm(
    const unsigned short* __restrict__ A,
    const unsigned short* __restrict__ B,
    const float* __restrict__ bias,
    void* __restrict__ C, int ldc,
    int K)
{
    __shared__ __align__(16) unsigned short As[2][128 * 32];
    __shared__ __align__(16) unsigned short Bs[2][128 * 32];

    const int tid  = threadIdx.x;
    const int lane = tid & 63;
    const int wave = tid >> 6;
    const int l16  = lane & 15;
    const int quad = lane >> 4;
    const int wm = (wave >> 1) * 64, wn = (wave & 1) * 64;
    const int bm = blockIdx.y, bn = blockIdx.x;

    const unsigned short* Ag = A + (size_t)(bm * 128) * K;
    const unsigned short* Bg = B + (size_t)(bn * 128) * K;

    // gload geometry: wave w call j -> LDS rows (w*2+j)*16..+15 (1KB/call)
    const int srow0 = wave * 32 + (lane >> 2);
    const int scol  = (lane & 3) * 8;
    const unsigned short* gA0 = Ag + (size_t)srow0 * K + scol;
    const unsigned short* gA1 = Ag + (size_t)(srow0 + 16) * K + scol;
    const unsigned short* gB0 = Bg + (size_t)srow0 * K + scol;
    const unsigned short* gB1 = Bg + (size_t)(srow0 + 16) * K + scol;

    auto stage = [&](int b, int kt) {
        gld16(&As[b][(wave * 2 + 0) * 512], gA0 + kt);
        gld16(&As[b][(wave * 2 + 1) * 512], gA1 + kt);
        gld16(&Bs[b][(wave * 2 + 0) * 512], gB0 + kt);
        gld16(&Bs[b][(wave * 2 + 1) * 512], gB1 + kt);
    };

    floatx4 acc[4][4] = {};
    const int NK = K >> 5;

    stage(0, 0);
    wait_vm0_barrier();

    for (int i = 0; i < NK; ++i) {
        const int cur = i & 1;
        if (i + 1 < NK) stage(cur ^ 1, (i + 1) * 32);

        bf16x8 af[4], bfr[4];
        #pragma unroll
        for (int mt = 0; mt < 4; ++mt)
            af[mt] = *(const bf16x8*)&As[cur][(wm + mt * 16 + l16) * 32 + quad * 8];
        #pragma unroll
        for (int nt = 0; nt < 4; ++nt)
            bfr[nt] = *(const bf16x8*)&Bs[cur][(wn + nt * 16 + l16) * 32 + quad * 8];
        #pragma unroll
        for (int mt = 0; mt < 4; ++mt)
            #pragma unroll
            for (int nt = 0; nt < 4; ++nt)
                acc[mt][nt] = mfma16(af[mt], bfr[nt], acc[mt][nt]);

        if (i + 1 < NK) wait_vm0_barrier();
        else            raw_barrier();
    }

    #pragma unroll
    for (int nt = 0; nt < 4; ++nt) {
        const int gcol = bn * 128 + wn + nt * 16 + l16;
        const float bv = BIAS ? bias[gcol] : 0.0f;
        #pragma unroll
        for (int mt = 0; mt < 4; ++mt) {
            #pragma unroll
            for (int r = 0; r < 4; ++r) {
                const int grow = bm * 128 + wm + mt * 16 + quad * 4 + r;
                float v = acc[mt][nt][r] + bv;
                if (OUTMODE == 0)
                    ((float*)C)[(size_t)grow * ldc + gcol] = v;
                else
                    ((unsigned short*)C)[(size_t)grow * ldc + gcol] = f2bf(v);
            }
        }
    }
}

// ============================================================
// Fused SwiGLU GEMM, 128x64 N-tile, 2-phase prefetch + fast silu:
// hid[m,n] = silu(A@W1^T + b1) * (A@W2^T + b2)
// ============================================================
__global__ __launch_bounds__(256) void mgemm_glu(
    const unsigned short* __restrict__ A,
    const unsigned short* __restrict__ B1,
    const unsigned short* __restrict__ B2,
    const float* __restrict__ bias1,
    const float* __restrict__ bias2,
    unsigned short* __restrict__ C, int ldc,
    int K)
{
    __shared__ __align__(16) unsigned short As[2][128 * 32];
    __shared__ __align__(16) unsigned short B1s[2][64 * 32];
    __shared__ __align__(16) unsigned short B2s[2][64 * 32];

    const int tid  = threadIdx.x;
    const int lane = tid & 63;
    const int wave = tid >> 6;
    const int l16  = lane & 15;
    const int quad = lane >> 4;
    const int wm = (wave >> 1) * 64, wn = (wave & 1) * 32;
    const int bm = blockIdx.y, bn = blockIdx.x;

    const unsigned short* Ag  = A  + (size_t)(bm * 128) * K;
    const unsigned short* B1g = B1 + (size_t)(bn * 64) * K;
    const unsigned short* B2g = B2 + (size_t)(bn * 64) * K;

    const int arow = wave * 32 + (lane >> 2);
    const int brow = wave * 16 + (lane >> 2);
    const int scol = (lane & 3) * 8;
    const unsigned short* gA0 = Ag  + (size_t)arow * K + scol;
    const unsigned short* gA1 = Ag  + (size_t)(arow + 16) * K + scol;
    const unsigned short* gB1 = B1g + (size_t)brow * K + scol;
    const unsigned short* gB2 = B2g + (size_t)brow * K + scol;

    auto stage = [&](int b, int kt) {
        gld16(&As[b][(wave * 2 + 0) * 512], gA0 + kt);
        gld16(&As[b][(wave * 2 + 1) * 512], gA1 + kt);
        gld16(&B1s[b][wave * 512], gB1 + kt);
        gld16(&B2s[b][wave * 512], gB2 + kt);
    };

    floatx4 acc1[4][2] = {};
    floatx4 acc2[4][2] = {};
    const int NK = K >> 5;

    stage(0, 0);
    wait_vm0_barrier();

    for (int i = 0; i < NK; ++i) {
        const int cur = i & 1;
        if (i + 1 < NK) stage(cur ^ 1, (i + 1) * 32);

        bf16x8 af[4], b1f[2], b2f[2];
        #pragma unroll
        for (int mt = 0; mt < 4; ++mt)
            af[mt] = *(const bf16x8*)&As[cur][(wm + mt * 16 + l16) * 32 + quad * 8];
        #pragma unroll
        for (int nt = 0; nt < 2; ++nt) {
            b1f[nt] = *(const bf16x8*)&B1s[cur][(wn + nt * 16 + l16) * 32 + quad * 8];
            b2f[nt] = *(const bf16x8*)&B2s[cur][(wn + nt * 16 + l16) * 32 + quad * 8];
        }
        #pragma unroll
        for (int mt = 0; mt < 4; ++mt)
            #pragma unroll
            for (int nt = 0; nt < 2; ++nt) {
                acc1[mt][nt] = mfma16(af[mt], b1f[nt], acc1[mt][nt]);
                acc2[mt][nt] = mfma16(af[mt], b2f[nt], acc2[mt][nt]);
            }

        if (i + 1 < NK) wait_vm0_barrier();
        else            raw_barrier();
    }

    #pragma unroll
    for (int nt = 0; nt < 2; ++nt) {
        const int gcol = bn * 64 + wn + nt * 16 + l16;
        const float b1 = bias1[gcol];
        const float b2 = bias2[gcol];
        #pragma unroll
        for (int mt = 0; mt < 4; ++mt) {
            #pragma unroll
            for (int r = 0; r < 4; ++r) {
                const int grow = bm * 128 + wm + mt * 16 + quad * 4 + r;
                const float x1 = acc1[mt][nt][r] + b1;
                const float x2 = acc2[mt][nt][r] + b2;
                // silu(x1)*x2 via HW exp2/rcp (log2e folded)
                const float e = fexp2(x1 * -1.44269504088896f);
                const float v = x1 * frcp(1.0f + e) * x2;
                C[(size_t)grow * ldc + gcol] = f2bf(v);
            }
        }
    }
}

// ============================================================
// QKV GEMM, 2-phase prefetch + fused epilogues:
//  q/k: fp32 RoPE (table), q pre-scaled by 0.125*log2e, -> Qb/Kb [bh][n][64]
//  v:   LDS-transposed (reuses dead As) -> Vtb [bh][d][n], 16B stores
// ============================================================
__global__ __launch_bounds__(256) void mgemm_qkv(
    const unsigned short* __restrict__ A,
    const unsigned short* __restrict__ B,
    const float* __restrict__ tab,
    unsigned short* __restrict__ Qb,
    unsigned short* __restrict__ Kb,
    unsigned short* __restrict__ Vtb)
{
    __shared__ __align__(16) unsigned short As[2][128 * 32];
    __shared__ __align__(16) unsigned short Bs[2][128 * 32];

    const int tid  = threadIdx.x;
    const int lane = tid & 63;
    const int wave = tid >> 6;
    const int l16  = lane & 15;
    const int quad = lane >> 4;
    const int wm = (wave >> 1) * 64, wn = (wave & 1) * 64;
    const int bm = blockIdx.y, bn = blockIdx.x;
    const int K = CDIM;

    const unsigned short* Ag = A + (size_t)(bm * 128) * K;
    const unsigned short* Bg = B + (size_t)(bn * 128) * K;

    const int srow0 = wave * 32 + (lane >> 2);
    const int scol  = (lane & 3) * 8;
    const unsigned short* gA0 = Ag + (size_t)srow0 * K + scol;
    const unsigned short* gA1 = Ag + (size_t)(srow0 + 16) * K + scol;
    const unsigned short* gB0 = Bg + (size_t)srow0 * K + scol;
    const unsigned short* gB1 = Bg + (size_t)(srow0 + 16) * K + scol;

    auto stage = [&](int b, int kt) {
        gld16(&As[b][(wave * 2 + 0) * 512], gA0 + kt);
        gld16(&As[b][(wave * 2 + 1) * 512], gA1 + kt);
        gld16(&Bs[b][(wave * 2 + 0) * 512], gB0 + kt);
        gld16(&Bs[b][(wave * 2 + 1) * 512], gB1 + kt);
    };

    floatx4 acc[4][4] = {};
    const int NK = K >> 5;

    stage(0, 0);
    wait_vm0_barrier();

    for (int i = 0; i < NK; ++i) {
        const int cur = i & 1;
        if (i + 1 < NK) stage(cur ^ 1, (i + 1) * 32);

        bf16x8 af[4], bfr[4];
        #pragma unroll
        for (int mt = 0; mt < 4; ++mt)
            af[mt] = *(const bf16x8*)&As[cur][(wm + mt * 16 + l16) * 32 + quad * 8];
        #pragma unroll
        for (int nt = 0; nt < 4; ++nt)
            bfr[nt] = *(const bf16x8*)&Bs[cur][(wn + nt * 16 + l16) * 32 + quad * 8];
        #pragma unroll
        for (int mt = 0; mt < 4; ++mt)
            #pragma unroll
            for (int nt = 0; nt < 4; ++nt)
                acc[mt][nt] = mfma16(af[mt], bfr[nt], acc[mt][nt]);

        if (i + 1 < NK) wait_vm0_barrier();
        else            raw_barrier();
    }

    // part is BLOCK-uniform: 128-col blocks never straddle a 1024 boundary.
    const int colbase0 = bn * 128;
    const int part = colbase0 >> 10;            // 0=q 1=k 2=v

    if (part == 2) {
        // ---- V: transpose via LDS (As dead), write Vtb [bh][d][n] ----
        unsigned short* T = &As[0][0];          // 4 waves x 64d x 16n ushorts
        #pragma unroll
        for (int mt = 0; mt < 4; ++mt) {
            __syncthreads();
            #pragma unroll
            for (int nt = 0; nt < 4; ++nt) {
                ushort4 pk;
                pk.x = f2bf(acc[mt][nt][0]); pk.y = f2bf(acc[mt][nt][1]);
                pk.z = f2bf(acc[mt][nt][2]); pk.w = f2bf(acc[mt][nt][3]);
                *(ushort4*)&T[((wave * 64 + nt * 16 + l16) * 16) + quad * 4] = pk;
            }
            __syncthreads();
            // 256 threads: w2 = tid>>6 (wave-tile), d = tid&63; 32B per thread
            const int w2 = tid >> 6, d = tid & 63;
            const int nrow0 = bm * 128 + (w2 >> 1) * 64 + mt * 16;
            const int b = nrow0 >> 11, n0 = nrow0 & 2047;
            const int h2 = ((bn * 128 + (w2 & 1) * 64) & 1023) >> 6;
            unsigned short* dst = Vtb +
                ((size_t)(b * NH + h2) * 64 + d) * 2048 + n0;
            const int tb = (w2 * 64 + d) * 16;
            *(uint4*)dst       = *(const uint4*)&T[tb];
            *(uint4*)(dst + 8) = *(const uint4*)&T[tb + 8];
        }
    } else {
        // ---- q/k: fp32 RoPE; q scaled by 0.125*log2e (exp2 softmax) ----
        const float qscale = (part == 0) ? 0.125f * 1.44269504088896f : 1.0f;
        const int h = ((colbase0 + wn) & 1023) >> 6;
        #pragma unroll
        for (int mt = 0; mt < 4; ++mt) {
            #pragma unroll
            for (int r = 0; r < 4; ++r) {
                const int grow = bm * 128 + wm + mt * 16 + quad * 4 + r;
                const int b = grow >> 11, n = grow & 2047;
                unsigned short* dst =
                    (part == 0 ? Qb : Kb) + ((size_t)(b * NH + h) * 2048 + n) * 64;
                #pragma unroll
                for (int nt = 0; nt < 2; ++nt) {
                    const int i = nt * 16 + l16;          // 0..31
                    const float c  = tab[(n * 32 + i) * 2];
                    const float sn = tab[(n * 32 + i) * 2 + 1];
                    const float x1 = acc[mt][nt][r];
                    const float x2v = acc[mt][nt + 2][r];
                    dst[i]      = f2bf((x1 * c - x2v * sn) * qscale);
                    dst[i + 32] = f2bf((x2v * c + x1 * sn) * qscale);
                }
            }
        }
    }
}

// ============================================================
// MFMA flash attention v4 (PROVEN R14): 128q blocks, 32x32x16,
// P in registers via cvt_pk + permlane32_swap. Grid (bh, qt).
// ============================================================
__global__ __launch_bounds__(256) void attn_mfma(
    const unsigned short* __restrict__ Qb,
    const unsigned short* __restrict__ Kb,
    const unsigned short* __restrict__ Vtb,
    unsigned short* __restrict__ Ob)
{
    const int bh = blockIdx.x;        // 0..63  (x-major: same-bh -> same XCD)
    const int qt = blockIdx.y;        // 0..15
    const int tid = threadIdx.x;
    const int lane = tid & 63, wave = tid >> 6;
    const int r32 = lane & 31, hi = lane >> 5;
    const int qrow = wave * 32 + r32; // this lane's query row in LDS

    __shared__ unsigned short QP[128][72];  // Q staging (held all iters)
    __shared__ unsigned short Ks[64][72];   // K tile [key][dim]
    __shared__ unsigned short Vs[64][72];   // V^T tile [dim][key]

    const unsigned short* Qg = Qb + ((size_t)bh * 2048 + qt * 128) * 64;
    const unsigned short* Kg = Kb + (size_t)bh * 2048 * 64;
    const unsigned short* Vg = Vtb + (size_t)bh * 64 * 2048;

    // stage Q tile 128x64
    #pragma unroll
    for (int rep = 0; rep < 4; ++rep) {
        const int c = tid + rep * 256;
        const int r = c >> 3, d0 = (c & 7) * 8;
        *(uint4*)&QP[r][d0] = *(const uint4*)(Qg + (size_t)r * 64 + d0);
    }

    // K/V staging slots for this thread (2 b128 each per tile)
    const int c0 = tid, c1 = tid + 256;
    const int kr0 = c0 >> 3, kd0 = (c0 & 7) * 8;
    const int kr1 = c1 >> 3, kd1 = (c1 & 7) * 8;

    // T14 prefetch tile 0 into regs
    uint4 ka0 = *(const uint4*)(Kg + (size_t)kr0 * 64 + kd0);
    uint4 ka1 = *(const uint4*)(Kg + (size_t)kr1 * 64 + kd1);
    uint4 va0 = *(const uint4*)(Vg + (size_t)kr0 * 2048 + kd0);
    uint4 va1 = *(const uint4*)(Vg + (size_t)kr1 * 2048 + kd1);

    __syncthreads();   // Q tile ready

    // Q B-frags (rows = wave's 32 queries), held for all iterations
    bf16x8 bq[4];
    #pragma unroll
    for (int f = 0; f < 4; ++f)
        bq[f] = *(const bf16x8*)&QP[qrow][f * 16 + hi * 8];

    floatx16 o0 = {}, o1 = {};      // O^T[d][q]: d-tiles 0..31 / 32..63
    float l_acc = 0.0f;

    for (int kt = 0; kt < 32; ++kt) {
        __syncthreads();   // prev tile's Ks/Vs frag reads complete
        *(uint4*)&Ks[kr0][kd0] = ka0;
        *(uint4*)&Ks[kr1][kd1] = ka1;
        *(uint4*)&Vs[kr0][kd0] = va0;
        *(uint4*)&Vs[kr1][kd1] = va1;
        if (kt + 1 < 32) {           // T14: issue next-tile loads now,
            const size_t nb = (size_t)(kt + 1) * 64;     // land during compute
            ka0 = *(const uint4*)(Kg + (nb + kr0) * 64 + kd0);
            ka1 = *(const uint4*)(Kg + (nb + kr1) * 64 + kd1);
            va0 = *(const uint4*)(Vg + (size_t)kr0 * 2048 + nb + kd0);
            va1 = *(const uint4*)(Vg + (size_t)kr1 * 2048 + nb + kd1);
        }
        __syncthreads();   // tile ready

        // ---- per 32-key subtile: S^T -> exp2 -> in-reg P -> PV ----
        #pragma unroll
        for (int t = 0; t < 2; ++t) {
            floatx16 s = {};
            #pragma unroll
            for (int f = 0; f < 4; ++f) {
                const bf16x8 ak = *(const bf16x8*)&Ks[t * 32 + r32][f * 16 + hi * 8];
                s = mfma32(ak, bq[f], s);
            }
            // p = exp2(s); rowsum
            float p[16];
            float rs = 0.0f;
            #pragma unroll
            for (int g = 0; g < 16; ++g) { p[g] = fexp2(s[g]); rs += p[g]; }
            l_acc += rs;
            // pack to bf16 words and swap halves across hi
            u32 w0 = cvtpk(p[0], p[1]),   w2 = cvtpk(p[4], p[5]);
            u32 w1 = cvtpk(p[2], p[3]),   w3 = cvtpk(p[6], p[7]);
            u32 w4 = cvtpk(p[8], p[9]),   w6 = cvtpk(p[12], p[13]);
            u32 w5 = cvtpk(p[10], p[11]), w7 = cvtpk(p[14], p[15]);
            asm("v_permlane32_swap_b32 %0, %1" : "+v"(w0), "+v"(w2));
            asm("v_permlane32_swap_b32 %0, %1" : "+v"(w1), "+v"(w3));
            asm("v_permlane32_swap_b32 %0, %1" : "+v"(w4), "+v"(w6));
            asm("v_permlane32_swap_b32 %0, %1" : "+v"(w5), "+v"(w7));
            uint4 u0; u0.x = w0; u0.y = w1; u0.z = w2; u0.w = w3;
            uint4 u1; u1.x = w4; u1.y = w5; u1.z = w6; u1.w = w7;
            const bf16x8 bp0 = __builtin_bit_cast(bf16x8, u0);  // keys t*32 + slot0
            const bf16x8 bp1 = __builtin_bit_cast(bf16x8, u1);  // keys t*32 + slot1
            // PV for this subtile's two 16-key slots (f = 2t, 2t+1)
            {
                const int f0 = 2 * t, f1 = 2 * t + 1;
                const bf16x8 av00 = *(const bf16x8*)&Vs[r32][f0 * 16 + hi * 8];
                const bf16x8 av01 = *(const bf16x8*)&Vs[32 + r32][f0 * 16 + hi * 8];
                o0 = mfma32(av00, bp0, o0);
                o1 = mfma32(av01, bp0, o1);
                const bf16x8 av10 = *(const bf16x8*)&Vs[r32][f1 * 16 + hi * 8];
                const bf16x8 av11 = *(const bf16x8*)&Vs[32 + r32][f1 * 16 + hi * 8];
                o0 = mfma32(av10, bp1, o0);
                o1 = mfma32(av11, bp1, o1);
            }
        }
    }

    // epilogue: lane's query = wave*32 + r32; lanes l/l+32 hold disjoint key
    // halves of the same query -> one shfl to complete l.
    const float l_tot = l_acc + __shfl_xor(l_acc, 32);
    const float inv = 1.0f / l_tot;
    const int b = bh >> 4, h = bh & 15;
    unsigned short* orow = Ob +
        (size_t)(b * SEQ + qt * 128 + qrow) * CDIM + h * 64;
    #pragma unroll
    for (int u = 0; u < 2; ++u) {
        const floatx16 ov = u ? o1 : o0;
        #pragma unroll
        for (int g = 0; g < 4; ++g) {
            ushort4 pk;
            pk.x = f2bf(ov[4 * g + 0] * inv); pk.y = f2bf(ov[4 * g + 1] * inv);
            pk.z = f2bf(ov[4 * g + 2] * inv); pk.w = f2bf(ov[4 * g + 3] * inv);
            // d = u*32 + 8g + 4*hi + (0..3)
            *(ushort4*)(orow + u * 32 + 8 * g + 4 * hi) = pk;
        }
    }
}

// ============================================================
// One-shot fp32 -> bf16 for all six tensors (block-uniform segments);
// RoPE table (fp64 angles)
// ============================================================
__global__ __launch_bounds__(256) void cvt_all(
    const float* __restrict__ x,    const float* __restrict__ qkv,
    const float* __restrict__ proj, const float* __restrict__ w1,
    const float* __restrict__ w2,   const float* __restrict__ w3,
    unsigned short* __restrict__ xb,    unsigned short* __restrict__ qkvb,
    unsigned short* __restrict__ projb, unsigned short* __restrict__ w1b,
    unsigned short* __restrict__ w2b,   unsigned short* __restrict__ w3b)
{
    const size_t i = ((size_t)blockIdx.x * 256 + threadIdx.x) * 4;
    const float* src; unsigned short* dst; size_t off;
    if      (i <  8388608) { src = x;    dst = xb;    off = 0; }
    else if (i < 11534336) { src = qkv;  dst = qkvb;  off = 8388608; }
    else if (i < 12582912) { src = proj; dst = projb; off = 11534336; }
    else if (i < 14680064) { src = w1;   dst = w1b;   off = 12582912; }
    else if (i < 16777216) { src = w2;   dst = w2b;   off = 14680064; }
    else                   { src = w3;   dst = w3b;   off = 16777216; }
    const size_t j = i - off;
    const float4 f = *(const float4*)(src + j);
    ushort4 o; o.x = f2bf(f.x); o.y = f2bf(f.y); o.z = f2bf(f.z); o.w = f2bf(f.w);
    *(ushort4*)(dst + j) = o;
}

__global__ __launch_bounds__(256) void rope_table(float* __restrict__ tab)
{
    const int idx = blockIdx.x * 256 + threadIdx.x;   // < 65536
    const int i = idx & 31, n = idx >> 5;
    const double f = (double)n * pow(10000.0, -(double)(2 * i) / 64.0);
    tab[idx * 2]     = (float)cos(f);
    tab[idx * 2 + 1] = (float)sin(f);
}

// ============================================================
// kernel_launch
// ============================================================
extern "C" void kernel_launch(void* const* d_in, const int* in_sizes, int n_in,
                              void* d_out, int out_size, void* d_ws, size_t ws_size,
                              hipStream_t stream)
{
    const float* x      = (const float*)d_in[0];
    const float* qkv_w  = (const float*)d_in[1];
    const float* proj_w = (const float*)d_in[2];
    const float* proj_b = (const float*)d_in[3];
    const float* w1_w   = (const float*)d_in[4];
    const float* w1_b   = (const float*)d_in[5];
    const float* w2_w   = (const float*)d_in[6];
    const float* w2_b   = (const float*)d_in[7];
    const float* w3_w   = (const float*)d_in[8];
    const float* w3_b   = (const float*)d_in[9];
    float* out = (float*)d_out;

    char* ws = (char*)d_ws;
    unsigned short* Qb    = (unsigned short*)(ws);              // [0,16M)
    unsigned short* Kb    = (unsigned short*)(ws + 16777216);   // [16,32M)
    unsigned short* Vtb   = (unsigned short*)(ws + 33554432);   // [32,48M)
    unsigned short* Ob    = (unsigned short*)(ws + 50331648);   // [48,64M)
    unsigned short* out1b = (unsigned short*)(ws + 67108864);   // [64,80M)
    unsigned short* w1b   = (unsigned short*)(ws + 83886080);   // [80,84M)
    unsigned short* w2b   = (unsigned short*)(ws + 88080384);   // [84,88M)
    unsigned short* w3b   = (unsigned short*)(ws + 92274688);   // [88,92M)
    unsigned short* projb = (unsigned short*)(ws + 96468992);   // [92,94M)
    unsigned short* xb    = (unsigned short*)(ws + 98566144);   // [94,110M)
    unsigned short* wqkvb = (unsigned short*)(ws + 115343360);  // [110,116M)
    float*          tab   = (float*)(ws + 121634816);           // [116,116.5M)
    unsigned short* hid   = (unsigned short*)(ws);              // [0,32M)

    const dim3 blk(256);

    // all fp32->bf16 conversions in one dispatch (18874368 elems / 1024)
    cvt_all<<<dim3(18432), blk, 0, stream>>>(
        x, qkv_w, proj_w, w1_w, w2_w, w3_w,
        xb, wqkvb, projb, w1b, w2b, w3b);
    rope_table<<<dim3(256), blk, 0, stream>>>(tab);

    // 1) QKV GEMM + fused rope/scale + coalesced transpose scatter
    mgemm_qkv<<<dim3(24, 64), blk, 0, stream>>>(xb, wqkvb, tab, Qb, Kb, Vtb);
    // 2) MFMA flash attention; grid (bh, qt) -> same-bh blocks co-XCD
    attn_mfma<<<dim3(BATCH * NH, SEQ / 128), blk, 0, stream>>>(Qb, Kb, Vtb, Ob);
    // 3) out1b = Ob @ projb^T + proj_b (bf16)
    mgemm<1, true><<<dim3(8, 64), blk, 0, stream>>>(
        Ob, projb, proj_b, out1b, CDIM, CDIM);
    // 4) hid = silu(out1b@w1^T + b1) * (out1b@w2^T + b2)  [fused, no x2]
    mgemm_glu<<<dim3(32, 64), blk, 0, stream>>>(
        out1b, w1b, w2b, w1_b, w2_b, hid, 2048, CDIM);
    // 5) out = hid @ w3b^T + w3_b (fp32 -> d_out)
    mgemm<0, true><<<dim3(8, 64), blk, 0, stream>>>(
        hid, w3b, w3_b, out, CDIM, 2048);
}